// Round 17
// baseline (354.603 us; speedup 1.0000x reference)
//
#include <hip/hip_runtime.h>
#include <hip/hip_bf16.h>

using u32 = unsigned int;
using u64 = unsigned long long;
using s8  = signed char;
typedef int i32x4  __attribute__((ext_vector_type(4)));
typedef int i32x16 __attribute__((ext_vector_type(16)));

__device__ __forceinline__ s8 tsign(float t){
  return (t > 0.f) ? (s8)1 : ((t < 0.f) ? (s8)-1 : (s8)0);
}
// threshold with precomputed scale: t = fl(fl(z*sc)+b) — identical roundings
__device__ __forceinline__ float bn_ts(float z, float sc, float b){
  return __fadd_rn(__fmul_rn(z, sc), b);
}

// ---------------------------------------------------------------------------
// w1 pack: bitplanes [co*2..], one ctl word per co at [256+co], flag at [384]
// ---------------------------------------------------------------------------
__global__ void pack_w1_k(const float* __restrict__ w1, u32* __restrict__ wp1){
  int lane = threadIdx.x;                 // one wave of 64
  bool hz = false;
  for (int h = 0; h < 2; h++){
    int co = h*64 + lane;
    u32 a = 0, s = 0, ctlw = 0;
    for (int tap = 0; tap < 9; tap++){
      float v0 = w1[(co*3 + 0)*9 + tap];
      float v1 = w1[(co*3 + 1)*9 + tap];
      float v2 = w1[(co*3 + 2)*9 + tap];
      int b0 = tap*3;
      a |= ((v0 != 0.f) ? 1u : 0u) << b0;     s |= ((v0 > 0.f) ? 1u : 0u) << b0;
      a |= ((v1 != 0.f) ? 1u : 0u) << (b0+1); s |= ((v1 > 0.f) ? 1u : 0u) << (b0+1);
      a |= ((v2 != 0.f) ? 1u : 0u) << (b0+2); s |= ((v2 > 0.f) ? 1u : 0u) << (b0+2);
      hz |= (v0 == 0.f) || (v1 == 0.f) || (v2 == 0.f);
      u32 f = (((v0 > 0.f) == (v1 > 0.f)) ? 1u : 0u)
            | ((v0 < 0.f) ? 2u : 0u)
            | ((v2 < 0.f) ? 4u : 0u);
      ctlw |= f << b0;
    }
    wp1[co*2]   = a;
    wp1[co*2+1] = s;
    wp1[256 + co] = ctlw;
  }
  u64 m = __ballot(hz);
  if (lane == 0) wp1[384] = (m != 0ull) ? 1u : 0u;
}

// ---------------------------------------------------------------------------
// MEGA prep+conv1 kernel. Block ranges:
//   [0,2048)      conv1 v9 (neighborhood cached once; couts in 4 chunks of 8,
//                 chunk loop FORCED non-unrolled -> ~60 VGPR live)
//   [2048,3712)   conv-weight MFMA fragment pack (w2..w6)
//   [3712,4736)   fc1 weight pack (K-permuted bitplanes)
//   [4736,5770)   fw2+fw3 bitplane pack
//   [5770,5786)   per-channel scales
// ---------------------------------------------------------------------------
__global__ __launch_bounds__(256) void mega_k(
    const float* __restrict__ x, const u32* __restrict__ wp1,
    const float* __restrict__ c1b, const float* __restrict__ g1,
    const float* __restrict__ bt1, s8* __restrict__ s1,
    const float* __restrict__ w2, const float* __restrict__ w3,
    const float* __restrict__ w4, const float* __restrict__ w5,
    const float* __restrict__ w6,
    s8* __restrict__ wf2, s8* __restrict__ wf3, s8* __restrict__ wf4,
    s8* __restrict__ wf5, s8* __restrict__ wf6,
    const float* __restrict__ fw1, u32* __restrict__ fw1p,
    const float* __restrict__ fw2, const float* __restrict__ fw3,
    u32* __restrict__ fw2p, u32* __restrict__ fw3p,
    const float* __restrict__ g2, const float* __restrict__ g3,
    const float* __restrict__ g4, const float* __restrict__ g5,
    const float* __restrict__ g6, const float* __restrict__ gf1,
    const float* __restrict__ gf2, const float* __restrict__ gf3,
    float* __restrict__ scb){
  __shared__ char smraw[8192];
  int b = blockIdx.x, tid = threadIdx.x;

  if (b < 2048){
    // ---------------- conv1 v9 --------------------------------------------
    int lane = tid & 63, wv = tid >> 6;
    int wid = b*4 + wv;              // 8192 waves: [n(128)][chunk(16)][coh(4)]
    int coh = wid & 3;
    int chunk = (wid >> 2) & 15;
    int n = wid >> 6;
    int py = lane >> 5, px = lane & 31;
    int y = chunk*2 + py;
    const float* xb = x + (size_t)n*3*1024;
    const float rs = __fdiv_rn(1.0f, __fsqrt_rn((float)(1.0 + 1e-5)));

    float xv[3][9];
    #pragma unroll
    for (int ci = 0; ci < 3; ci++)
      #pragma unroll
      for (int tap = 0; tap < 9; tap++){
        int yy = y + tap/3 - 1, xx = px + tap%3 - 1;
        bool ok = ((unsigned)yy < 32u) && ((unsigned)xx < 32u);
        xv[ci][tap] = ok ? xb[(ci*32 + yy)*32 + xx] : 0.f;
      }

    size_t pixbase = (((size_t)n*1024) + y*32 + px)*128 + coh*32;
    bool fallback = (wp1[384] != 0u);

    if (!fallback){
      #pragma unroll 1
      for (int c8 = 0; c8 < 4; c8++){         // forced rolled: 8 accs live max
        float acc[8]; u32 ctl[8];
        #pragma unroll
        for (int j = 0; j < 8; j++){
          acc[j] = 0.f;
          ctl[j] = wp1[256 + coh*32 + c8*8 + j];   // wave-uniform
        }
        #pragma unroll
        for (int tap = 0; tap < 9; tap++){
          float pc0 = __fadd_rn(xv[0][tap], xv[1][tap]);
          float pc1 = __fadd_rn(xv[0][tap], -xv[1][tap]);
          float x2 = xv[2][tap];
          #pragma unroll
          for (int j = 0; j < 8; j++){
            u32 f = ctl[j] >> (3*tap);
            float s01 = (f & 1u) ? pc0 : pc1;
            s01 = __uint_as_float(__float_as_uint(s01) ^ ((f & 2u) << 30));
            float t2 = __uint_as_float(__float_as_uint(x2) ^ ((f & 4u) << 29));
            acc[j] = __fadd_rn(acc[j], __fadd_rn(s01, t2));
          }
        }
        u32 ow0 = 0, ow1 = 0;
        #pragma unroll
        for (int j = 0; j < 8; j++){
          int co = coh*32 + c8*8 + j;
          float v = __fadd_rn(acc[j], c1b[co]);
          float t = bn_ts(v, __fmul_rn(g1[co], rs), bt1[co]);
          u32 bv = (u32)(unsigned char)tsign(t);
          if (j < 4) ow0 |= bv << (8*j); else ow1 |= bv << (8*(j-4));
        }
        uint2 st = { ow0, ow1 };
        *reinterpret_cast<uint2*>(&s1[pixbase + c8*8]) = st;
      }
    } else {
      #pragma unroll 1
      for (int c8 = 0; c8 < 4; c8++){
        float acc[8]; u32 wAv[8], wSv[8];
        #pragma unroll
        for (int j = 0; j < 8; j++){
          acc[j] = 0.f;
          int co = coh*32 + c8*8 + j;
          wAv[j] = wp1[co*2]; wSv[j] = wp1[co*2+1];
        }
        #pragma unroll
        for (int tap = 0; tap < 9; tap++){
          #pragma unroll
          for (int j = 0; j < 8; j++){
            int bit = tap*3;
            float pt = 0.f;
            float sg0 = ((wAv[j] >> bit) & 1u) ? (((wSv[j] >> bit) & 1u) ? 1.f : -1.f) : 0.f;
            pt = __fadd_rn(pt, __fmul_rn(sg0, xv[0][tap]));
            float sg1 = ((wAv[j] >> (bit+1)) & 1u) ? (((wSv[j] >> (bit+1)) & 1u) ? 1.f : -1.f) : 0.f;
            pt = __fadd_rn(pt, __fmul_rn(sg1, xv[1][tap]));
            float sg2 = ((wAv[j] >> (bit+2)) & 1u) ? (((wSv[j] >> (bit+2)) & 1u) ? 1.f : -1.f) : 0.f;
            pt = __fadd_rn(pt, __fmul_rn(sg2, xv[2][tap]));
            acc[j] = __fadd_rn(acc[j], pt);
          }
        }
        u32 ow0 = 0, ow1 = 0;
        #pragma unroll
        for (int j = 0; j < 8; j++){
          int co = coh*32 + c8*8 + j;
          float v = __fadd_rn(acc[j], c1b[co]);
          float t = bn_ts(v, __fmul_rn(g1[co], rs), bt1[co]);
          u32 bv = (u32)(unsigned char)tsign(t);
          if (j < 4) ow0 |= bv << (8*j); else ow1 |= bv << (8*(j-4));
        }
        uint2 st = { ow0, ow1 };
        *reinterpret_cast<uint2*>(&s1[pixbase + c8*8]) = st;
      }
    }
  } else if (b < 3712){
    // ---------------- conv-weight MFMA fragment pack -----------------------
    int bb = b - 2048;
    const float* w; s8* wf; int CIN, COUT, co;
    if      (bb < 128) { w=w2; wf=wf2; CIN=128; COUT=128; co=bb; }
    else if (bb < 384) { w=w3; wf=wf3; CIN=128; COUT=256; co=bb-128; }
    else if (bb < 640) { w=w4; wf=wf4; CIN=256; COUT=256; co=bb-384; }
    else if (bb < 1152){ w=w5; wf=wf5; CIN=256; COUT=512; co=bb-640; }
    else               { w=w6; wf=wf6; CIN=512; COUT=512; co=bb-1152; }
    s8* sb = (s8*)smraw;
    int nf = CIN*9;
    const float* wb = w + (size_t)co*nf;
    for (int i = tid; i < nf; i += 256){
      float v = wb[i];
      sb[i] = (v > 0.f) ? (s8)1 : ((v < 0.f) ? (s8)-1 : (s8)0);
    }
    __syncthreads();
    int KK = CIN >> 5, CG = COUT >> 5;
    int cg = co >> 5, llo = co & 31;
    for (int i = tid; i < nf; i += 256){
      int tap = i / CIN, k = i - tap*CIN;
      s8 v = sb[k*9 + tap];
      size_t dst = ((((size_t)tap*KK + (k>>5))*CG + cg)*64
                    + (llo + ((k>>4)&1)*32))*16 + (k&15);
      wf[dst] = v;
    }
  } else if (b < 4736){
    // ---------------- fc1 pack: k = c*16 + px, kw = px*16 + cw --------------
    int co = b - 3712;
    unsigned char* sb = (unsigned char*)smraw;
    const float* wb = fw1 + (size_t)co*8192;
    for (int i = tid; i < 8192; i += 256){
      float v = wb[i];
      sb[i] = (unsigned char)(((v != 0.f) ? 2u : 0u) | ((v > 0.f) ? 1u : 0u));
    }
    __syncthreads();
    int kw = tid;
    int px = kw >> 4, cw = kw & 15;
    u32 a = 0, s = 0;
    for (int j = 0; j < 32; j++){
      unsigned char bch = sb[(cw*32 + j)*16 + px];
      a |= (u32)(bch >> 1) << j;
      s |= (u32)(bch & 1u) << j;
    }
    size_t o = ((size_t)kw*1024 + co)*2;
    fw1p[o] = a; fw1p[o+1] = s;
  } else if (b < 5770){
    // ---------------- fw2 + fw3 bitplane pack -------------------------------
    int bb = b - 4736;
    const float* w; u32* wp; int COUT, co;
    if (bb < 1024){ w = fw2; wp = fw2p; COUT = 1024; co = bb; }
    else          { w = fw3; wp = fw3p; COUT = 10;   co = bb-1024; }
    unsigned char* sb = (unsigned char*)smraw;
    const float* wbp = w + (size_t)co*1024;
    for (int i = tid; i < 1024; i += 256){
      float v = wbp[i];
      sb[i] = (unsigned char)(((v != 0.f) ? 2u : 0u) | ((v > 0.f) ? 1u : 0u));
    }
    __syncthreads();
    for (int kw = tid; kw < 32; kw += 256){
      u32 a = 0, s = 0;
      for (int j = 0; j < 32; j++){
        unsigned char bch = sb[kw*32 + j];
        a |= (u32)(bch >> 1) << j;
        s |= (u32)(bch & 1u) << j;
      }
      size_t o = ((size_t)kw*COUT + co)*2;
      wp[o] = a; wp[o+1] = s;
    }
  } else {
    // ---------------- per-channel scales ------------------------------------
    int i = (b - 5770)*256 + tid;
    const float rs = __fdiv_rn(1.0f, __fsqrt_rn((float)(1.0 + 1e-5)));
    float v;
    if      (i < 128)  v = g1[i];
    else if (i < 256)  v = g2[i-128];
    else if (i < 512)  v = g3[i-256];
    else if (i < 768)  v = g4[i-512];
    else if (i < 1280) v = g5[i-768];
    else if (i < 1792) v = g6[i-1280];
    else if (i < 2816) v = gf1[i-1792];
    else if (i < 3840) v = gf2[i-2816];
    else if (i < 3850) v = gf3[i-3840];
    else return;
    scb[i] = __fmul_rn(v, rs);
  }
}

// ---------------------------------------------------------------------------
// MFMA ternary bconv: CGB=2, block-shared cout-group, per-tap B-slice staged
// global->LDS double-buffered. WPB=4 (r14 config — grid, not LDS, limits
// occupancy at the small layers; wider blocks only widen barriers).
// ---------------------------------------------------------------------------
template<int CIN, int COUT, int H, int W, int POOL, int BITOUT, int WPB>
__global__ __launch_bounds__(WPB*64) void bconv_l(
    const s8* __restrict__ A, const s8* __restrict__ WF,
    const float* __restrict__ sc, const float* __restrict__ bt,
    s8* __restrict__ O, u32* __restrict__ OB){
  constexpr int KK = CIN/32, CG = COUT/32, CGB = 2;
  constexpr int XT = (W >= 16) ? 16 : 8;
  constexpr int YT = 32 / XT;
  constexpr int TPR = W / XT;
  constexpr int TROWS = H / YT;
  constexpr int NMT = 128*TROWS*TPR;
  constexpr int HO = POOL ? H/2 : H, WO = POOL ? W/2 : W;
  constexpr int RY = (XT == 16) ? 8 : 4;
  constexpr int TAPB = KK*CGB*1024;          // bytes per tap B-slice
  constexpr int NT = WPB*64;
  __shared__ s8 Bsh[2][TAPB];

  int tid = threadIdx.x, lane = tid & 63, wv = tid >> 6;
  int wid = blockIdx.x*WPB + wv;
  int mt = wid % NMT; int cb = wid / NMT;    // NMT%WPB==0 -> cb uniform/block
  int tx = mt % TPR; int r0 = mt / TPR;
  int ty = r0 % TROWS; int n = r0 / TROWS;
  int y0 = ty*YT, x0 = tx*XT;
  int p = lane & 31;
  int py = p / XT, px = p % XT;
  int y = y0 + py, x = x0 + px;
  int kh = lane >> 5;
  const s8* An = A + (size_t)n*H*W*CIN;

  auto stage = [&](int buf, int tap){
    const s8* src0 = WF + (((size_t)tap*KK)*CG + (size_t)cb*CGB)*1024;
    #pragma unroll
    for (int j = 0; j < TAPB/(NT*16); j++){
      int byte = (tid + j*NT)*16;
      int kk = byte / (CGB*1024);
      int rem = byte - kk*(CGB*1024);
      *reinterpret_cast<uint4*>(&Bsh[buf][byte]) =
        *reinterpret_cast<const uint4*>(src0 + (size_t)kk*CG*1024 + rem);
    }
  };

  i32x16 acc0 = {0,0,0,0,0,0,0,0,0,0,0,0,0,0,0,0};
  i32x16 acc1 = acc0;

  stage(0, 0);
  __syncthreads();
  int buf = 0;
  #pragma unroll
  for (int tap = 0; tap < 9; tap++){
    if (tap < 8) stage(buf^1, tap+1);        // overlap next-tap staging
    int dy = tap/3 - 1, dx = tap%3 - 1;
    int sy = y + dy, sx = x + dx;
    bool ok = ((unsigned)sy < (unsigned)H) && ((unsigned)sx < (unsigned)W);
    const s8* ap = An + ((size_t)sy*W + sx)*CIN + kh*16;
    #pragma unroll
    for (int kk = 0; kk < KK; kk++){
      i32x4 av = {0,0,0,0};
      if (ok) av = *reinterpret_cast<const i32x4*>(ap + kk*32);
      i32x4 b0 = *reinterpret_cast<const i32x4*>(&Bsh[buf][(kk*CGB+0)*1024 + lane*16]);
      i32x4 b1 = *reinterpret_cast<const i32x4*>(&Bsh[buf][(kk*CGB+1)*1024 + lane*16]);
      acc0 = __builtin_amdgcn_mfma_i32_32x32x32_i8(av, b0, acc0, 0, 0, 0);
      acc1 = __builtin_amdgcn_mfma_i32_32x32x32_i8(av, b1, acc1, 0, 0, 0);
    }
    __syncthreads();                          // staged writes visible
    buf ^= 1;
  }

  auto epi = [&](const i32x16& acc, int cgb){
    int co = (cb*CGB + cgb)*32 + (lane & 31);
    float ss = sc[co], bb = bt[co];
    if (POOL){
      #pragma unroll
      for (int q = 0; q < 4; q++){
        int rr = (q&1)*2 + (q>>1)*((XT == 16) ? 4 : 8);
        int z = max(max(acc[rr], acc[rr+1]), max(acc[rr+RY], acc[rr+RY+1]));
        float t = bn_ts((float)z, ss, bb);
        if (!BITOUT){
          int pb = (rr&3) + 8*(rr>>2) + 4*kh;
          int yy = y0 + pb/XT, xx2 = x0 + pb%XT;
          int oy = yy >> 1, ox = xx2 >> 1;
          O[(((size_t)n*HO + oy)*WO + ox)*COUT + co] = tsign(t);
        } else {
          u64 mP = __ballot(t > 0.f);
          u64 mN = __ballot(t < 0.f);
          if (lane == 0){
            u64 mA = mP | mN;
            int cw = cb*CGB + cgb;
            int pb0 = (rr&3) + 8*(rr>>2);
            int yy0 = y0 + pb0/XT, xx0 = x0 + pb0%XT;
            int p0 = (yy0>>1)*4 + (xx0>>1);
            int pb1 = pb0 + 4;
            int yy1 = y0 + pb1/XT, xx1 = x0 + pb1%XT;
            int p1 = (yy1>>1)*4 + (xx1>>1);
            size_t o0 = ((size_t)n*256 + p0*16 + cw)*2;
            size_t o1 = ((size_t)n*256 + p1*16 + cw)*2;
            OB[o0]   = (u32)mA;       OB[o0+1] = (u32)mP;
            OB[o1]   = (u32)(mA>>32); OB[o1+1] = (u32)(mP>>32);
          }
        }
      }
    } else {
      #pragma unroll
      for (int rr = 0; rr < 16; rr++){
        int pb = (rr&3) + 8*(rr>>2) + 4*kh;
        int yy = y0 + pb/XT, xx2 = x0 + pb%XT;
        float t = bn_ts((float)acc[rr], ss, bb);
        O[(((size_t)n*H + yy)*W + xx2)*COUT + co] = tsign(t);
      }
    }
  };
  epi(acc0, 0); epi(acc1, 1);
}

// ---------------------------------------------------------------------------
// Fused FC stack: fc1 (K=8192) -> fc2 (K=1024) -> fc3 + log_softmax.
// ---------------------------------------------------------------------------
__global__ __launch_bounds__(256) void fc_all_k(
    const u32* __restrict__ A0, const u32* __restrict__ W1,
    const float* __restrict__ fb1, const float* __restrict__ sc1f,
    const float* __restrict__ bt1f,
    const u32* __restrict__ W2, const float* __restrict__ fb2,
    const float* __restrict__ sc2f, const float* __restrict__ bt2f,
    const u32* __restrict__ W3, const float* __restrict__ fb3,
    const float* __restrict__ sc3f, const float* __restrict__ bt3f,
    float* __restrict__ out){
  int n = blockIdx.x, tid = threadIdx.x;
  __shared__ u32 Ash[512];
  __shared__ s8 tern[1024];
  __shared__ double ls[10];
  for (int i = tid; i < 512; i += 256) Ash[i] = A0[(size_t)n*512 + i];
  __syncthreads();
  // fc1: 4 outputs / thread
  int z1[4] = {0,0,0,0};
  for (int kw = 0; kw < 256; kw++){
    u32 aA = Ash[kw*2], aS = Ash[kw*2+1];
    #pragma unroll
    for (int q = 0; q < 4; q++){
      int o = tid + q*256;
      uint2 w = reinterpret_cast<const uint2*>(W1)[kw*1024 + o];
      u32 v = aA & w.x; u32 d = v & (aS ^ w.y);
      z1[q] += __popc(v) - 2*__popc(d);
    }
  }
  #pragma unroll
  for (int q = 0; q < 4; q++){
    int o = tid + q*256;
    float vv = __fadd_rn((float)z1[q], fb1[o]);
    tern[o] = tsign(bn_ts(vv, sc1f[o], bt1f[o]));
  }
  __syncthreads();
  if (tid < 32){
    u32 a = 0, s = 0;
    for (int j = 0; j < 32; j++){
      s8 v = tern[tid*32 + j];
      a |= (u32)(v != 0) << j; s |= (u32)(v > 0) << j;
    }
    Ash[tid*2] = a; Ash[tid*2+1] = s;
  }
  __syncthreads();
  // fc2
  int z2[4] = {0,0,0,0};
  for (int kw = 0; kw < 32; kw++){
    u32 aA = Ash[kw*2], aS = Ash[kw*2+1];
    #pragma unroll
    for (int q = 0; q < 4; q++){
      int o = tid + q*256;
      uint2 w = reinterpret_cast<const uint2*>(W2)[kw*1024 + o];
      u32 v = aA & w.x; u32 d = v & (aS ^ w.y);
      z2[q] += __popc(v) - 2*__popc(d);
    }
  }
  #pragma unroll
  for (int q = 0; q < 4; q++){
    int o = tid + q*256;
    float vv = __fadd_rn((float)z2[q], fb2[o]);
    tern[o] = tsign(bn_ts(vv, sc2f[o], bt2f[o]));
  }
  __syncthreads();
  if (tid < 32){
    u32 a = 0, s = 0;
    for (int j = 0; j < 32; j++){
      s8 v = tern[tid*32 + j];
      a |= (u32)(v != 0) << j; s |= (u32)(v > 0) << j;
    }
    Ash[tid*2] = a; Ash[tid*2+1] = s;
  }
  __syncthreads();
  // fc3 + log_softmax (f64 tail)
  if (tid < 10){
    int z = 0;
    for (int kw = 0; kw < 32; kw++){
      u32 aA = Ash[kw*2], aS = Ash[kw*2+1];
      uint2 w = reinterpret_cast<const uint2*>(W3)[kw*10 + tid];
      u32 v = aA & w.x; u32 d = v & (aS ^ w.y);
      z += __popc(v) - 2*__popc(d);
    }
    float vv = __fadd_rn((float)z, fb3[tid]);
    ls[tid] = (double)bn_ts(vv, sc3f[tid], bt3f[tid]);
  }
  __syncthreads();
  if (tid < 10){
    double m = -1e300;
    for (int j = 0; j < 10; j++) m = fmax(m, ls[j]);
    double sum = 0.0;
    for (int j = 0; j < 10; j++) sum += exp(ls[j] - m);
    out[n*10 + tid] = (float)(ls[tid] - m - log(sum));
  }
}

extern "C" void kernel_launch(void* const* d_in, const int* in_sizes, int n_in,
                              void* d_out, int out_size, void* d_ws, size_t ws_size,
                              hipStream_t stream){
  auto f = [&](int i){ return (const float*)d_in[i]; };
  const float *x  = f(0),  *w1 = f(1),  *c1b = f(2),
    *w2 = f(3),  *w3 = f(4),  *w4 = f(5),  *w5 = f(6),  *w6 = f(7),
    *fw1 = f(8), *fb1 = f(9), *fw2 = f(10), *fb2 = f(11),
    *fw3 = f(12), *fb3 = f(13),
    *g1 = f(14), *bt1 = f(15), *g2 = f(16), *bt2 = f(17),
    *g3 = f(18), *bt3 = f(19), *g4 = f(20), *bt4 = f(21),
    *g5 = f(22), *bt5 = f(23), *g6 = f(24), *bt6 = f(25),
    *gf1 = f(26), *btf1 = f(27), *gf2 = f(28), *btf2 = f(29),
    *gf3 = f(30), *btf3 = f(31);

  char* base = (char*)d_ws;
  size_t off = 0;
  auto alloc = [&](size_t bytes){ char* p = base + off; off += (bytes + 255) & ~(size_t)255; return p; };
  s8* poolA = (s8*)alloc(128ull*32*32*128);       // s1 / s3 / s5
  s8* poolB = (s8*)alloc(128ull*16*16*128);       // s2 / s4
  s8 *s1 = poolA, *s3 = poolA, *s5 = poolA;
  s8 *s2 = poolB, *s4 = poolB;
  s8 *wf2 = (s8*)alloc(9ull*128*128), *wf3 = (s8*)alloc(9ull*128*256),
     *wf4 = (s8*)alloc(9ull*256*256), *wf5 = (s8*)alloc(9ull*256*512),
     *wf6 = (s8*)alloc(9ull*512*512);
  u32 *wp1  = (u32*)alloc(385*4);                 // bitplanes + ctl + flag
  float* scb = (float*)alloc(3850*4);             // per-channel scales
  u32 *fw1p = (u32*)alloc(2ull*256*1024*4), *fw2p = (u32*)alloc(2ull*32*1024*4),
      *fw3p = (u32*)alloc(2ull*32*10*4);
  u32 *s6p  = (u32*)alloc(2ull*128*256*4);

  float *sc2 = scb+128, *sc3 = scb+256, *sc4 = scb+512,
        *sc5 = scb+768, *sc6 = scb+1280, *scf1 = scb+1792, *scf2 = scb+2816,
        *scf3 = scb+3840;

  // dispatch 1: tiny w1 pack (conv1 in mega depends on it)
  pack_w1_k<<<1, 64, 0, stream>>>(w1, wp1);
  // dispatch 2: conv1 || all weight packing || scales
  mega_k<<<5786, 256, 0, stream>>>(
      x, wp1, c1b, g1, bt1, s1,
      w2, w3, w4, w5, w6, wf2, wf3, wf4, wf5, wf6,
      fw1, fw1p, fw2, fw3, fw2p, fw3p,
      g2, g3, g4, g5, g6, gf1, gf2, gf3, scb);

  // network — blocks = NMT*(CG/2)/WPB, WPB=4
  bconv_l<128,128,32,32,1,0,4><<<2048, 256, 0, stream>>>(s1, wf2, sc2, bt2, s2, nullptr);
  bconv_l<128,256,16,16,0,0,4><<<1024, 256, 0, stream>>>(s2, wf3, sc3, bt3, s3, nullptr);
  bconv_l<256,256,16,16,1,0,4><<<1024, 256, 0, stream>>>(s3, wf4, sc4, bt4, s4, nullptr);
  bconv_l<256,512, 8, 8,0,0,4><<< 512, 256, 0, stream>>>(s4, wf5, sc5, bt5, s5, nullptr);
  bconv_l<512,512, 8, 8,1,1,4><<< 512, 256, 0, stream>>>(s5, wf6, sc6, bt6, nullptr, s6p);
  fc_all_k<<<128, 256, 0, stream>>>(s6p, fw1p, fb1, scf1, btf1,
                                    fw2p, fb2, scf2, btf2,
                                    fw3p, fb3, scf3, btf3, (float*)d_out);
}

// Round 18
// 286.605 us; speedup vs baseline: 1.2373x; 1.2373x over previous
//
#include <hip/hip_runtime.h>
#include <hip/hip_bf16.h>

using u32 = unsigned int;
using u64 = unsigned long long;
using s8  = signed char;
typedef int i32x4  __attribute__((ext_vector_type(4)));
typedef int i32x16 __attribute__((ext_vector_type(16)));

__device__ __forceinline__ s8 tsign(float t){
  return (t > 0.f) ? (s8)1 : ((t < 0.f) ? (s8)-1 : (s8)0);
}
// threshold with precomputed scale: t = fl(fl(z*sc)+b) — identical roundings
__device__ __forceinline__ float bn_ts(float z, float sc, float b){
  return __fadd_rn(__fmul_rn(z, sc), b);
}

// ---------------------------------------------------------------------------
// w1 pack: bitplanes [co*2..], one ctl word per co at [256+co], flag at [384]
// ---------------------------------------------------------------------------
__global__ void pack_w1_k(const float* __restrict__ w1, u32* __restrict__ wp1){
  int lane = threadIdx.x;                 // one wave of 64
  bool hz = false;
  for (int h = 0; h < 2; h++){
    int co = h*64 + lane;
    u32 a = 0, s = 0, ctlw = 0;
    for (int tap = 0; tap < 9; tap++){
      float v0 = w1[(co*3 + 0)*9 + tap];
      float v1 = w1[(co*3 + 1)*9 + tap];
      float v2 = w1[(co*3 + 2)*9 + tap];
      int b0 = tap*3;
      a |= ((v0 != 0.f) ? 1u : 0u) << b0;     s |= ((v0 > 0.f) ? 1u : 0u) << b0;
      a |= ((v1 != 0.f) ? 1u : 0u) << (b0+1); s |= ((v1 > 0.f) ? 1u : 0u) << (b0+1);
      a |= ((v2 != 0.f) ? 1u : 0u) << (b0+2); s |= ((v2 > 0.f) ? 1u : 0u) << (b0+2);
      hz |= (v0 == 0.f) || (v1 == 0.f) || (v2 == 0.f);
      u32 f = (((v0 > 0.f) == (v1 > 0.f)) ? 1u : 0u)
            | ((v0 < 0.f) ? 2u : 0u)
            | ((v2 < 0.f) ? 4u : 0u);
      ctlw |= f << b0;
    }
    wp1[co*2]   = a;
    wp1[co*2+1] = s;
    wp1[256 + co] = ctlw;
  }
  u64 m = __ballot(hz);
  if (lane == 0) wp1[384] = (m != 0ull) ? 1u : 0u;
}

// ---------------------------------------------------------------------------
// MEGA prep+conv1 kernel (r14 structure). Block ranges:
//   [0,2048)      conv1 (r14 version: 32 couts/wave, reload-style, 44 VGPR)
//   [2048,3712)   conv-weight MFMA fragment pack (w2..w6) — uint4 stores
//   [3712,4736)   fc1 weight pack (K-permuted bitplanes)
//   [4736,5770)   fw2+fw3 bitplane pack
//   [5770,5786)   per-channel scales
// ---------------------------------------------------------------------------
__global__ __launch_bounds__(256) void mega_k(
    const float* __restrict__ x, const u32* __restrict__ wp1,
    const float* __restrict__ c1b, const float* __restrict__ g1,
    const float* __restrict__ bt1, s8* __restrict__ s1,
    const float* __restrict__ w2, const float* __restrict__ w3,
    const float* __restrict__ w4, const float* __restrict__ w5,
    const float* __restrict__ w6,
    s8* __restrict__ wf2, s8* __restrict__ wf3, s8* __restrict__ wf4,
    s8* __restrict__ wf5, s8* __restrict__ wf6,
    const float* __restrict__ fw1, u32* __restrict__ fw1p,
    const float* __restrict__ fw2, const float* __restrict__ fw3,
    u32* __restrict__ fw2p, u32* __restrict__ fw3p,
    const float* __restrict__ g2, const float* __restrict__ g3,
    const float* __restrict__ g4, const float* __restrict__ g5,
    const float* __restrict__ g6, const float* __restrict__ gf1,
    const float* __restrict__ gf2, const float* __restrict__ gf3,
    float* __restrict__ scb){
  __shared__ char smraw[8192];
  int b = blockIdx.x, tid = threadIdx.x;

  if (b < 2048){
    // ---------------- conv1 (r14): 32 couts/wave, non-unrolled co loop -----
    int lane = tid & 63, wv = tid >> 6;
    int wid = b*4 + wv;              // 8192 waves: [n(128)][chunk(16)][coh(4)]
    int coh = wid & 3;
    int chunk = (wid >> 2) & 15;
    int n = wid >> 6;
    int py = lane >> 5, px = lane & 31;
    int y = chunk*2 + py;
    const float* xb = x + (size_t)n*3*1024;
    const float rs = __fdiv_rn(1.0f, __fsqrt_rn((float)(1.0 + 1e-5)));

    float xv[3][9];
    #pragma unroll
    for (int ci = 0; ci < 3; ci++)
      #pragma unroll
      for (int tap = 0; tap < 9; tap++){
        int yy = y + tap/3 - 1, xx = px + tap%3 - 1;
        bool ok = ((unsigned)yy < 32u) && ((unsigned)xx < 32u);
        xv[ci][tap] = ok ? xb[(ci*32 + yy)*32 + xx] : 0.f;
      }
    float pc0[9], pc1[9];
    #pragma unroll
    for (int tap = 0; tap < 9; tap++){
      pc0[tap] = __fadd_rn(xv[0][tap], xv[1][tap]);
      pc1[tap] = __fadd_rn(xv[0][tap], -xv[1][tap]);
    }

    size_t pixbase = (((size_t)n*1024) + y*32 + px)*128 + coh*32;
    bool fallback = (wp1[384] != 0u);

    if (!fallback){
      for (int co4 = 0; co4 < 32; co4 += 4){
        u32 outw = 0;
        #pragma unroll
        for (int j = 0; j < 4; j++){
          int co = coh*32 + co4 + j;
          u32 ctlw = wp1[256 + co];          // wave-uniform
          float acc = 0.f;
          #pragma unroll
          for (int tap = 0; tap < 9; tap++){
            u32 f = ctlw >> (3*tap);
            float s01 = (f & 1u) ? pc0[tap] : pc1[tap];
            s01 = __uint_as_float(__float_as_uint(s01) ^ ((f & 2u) << 30));
            float t2 = __uint_as_float(__float_as_uint(xv[2][tap]) ^ ((f & 4u) << 29));
            acc = __fadd_rn(acc, __fadd_rn(s01, t2));
          }
          float v = __fadd_rn(acc, c1b[co]);
          float t = bn_ts(v, __fmul_rn(g1[co], rs), bt1[co]);
          outw |= ((u32)(unsigned char)tsign(t)) << (8*j);
        }
        *reinterpret_cast<u32*>(&s1[pixbase + co4]) = outw;
      }
    } else {
      for (int co4 = 0; co4 < 32; co4 += 4){
        u32 outw = 0;
        #pragma unroll
        for (int j = 0; j < 4; j++){
          int co = coh*32 + co4 + j;
          u32 wA = wp1[co*2], wS = wp1[co*2+1];
          float acc = 0.f;
          #pragma unroll
          for (int tap = 0; tap < 9; tap++){
            float pt = 0.f;
            #pragma unroll
            for (int ci = 0; ci < 3; ci++){
              int bit = tap*3 + ci;
              float sg = ((wA >> bit) & 1u) ? (((wS >> bit) & 1u) ? 1.f : -1.f) : 0.f;
              pt = __fadd_rn(pt, __fmul_rn(sg, xv[ci][tap]));
            }
            acc = __fadd_rn(acc, pt);
          }
          float v = __fadd_rn(acc, c1b[co]);
          float t = bn_ts(v, __fmul_rn(g1[co], rs), bt1[co]);
          outw |= ((u32)(unsigned char)tsign(t)) << (8*j);
        }
        *reinterpret_cast<u32*>(&s1[pixbase + co4]) = outw;
      }
    }
  } else if (b < 3712){
    // -------- conv-weight MFMA fragment pack, vectorized uint4 stores ------
    // dst run of 16 bytes (fixed tap,kk,kh): byte e <- sb[(kk*32+kh*16+e)*9+tap]
    int bb = b - 2048;
    const float* w; s8* wf; int CIN, COUT, co;
    if      (bb < 128) { w=w2; wf=wf2; CIN=128; COUT=128; co=bb; }
    else if (bb < 384) { w=w3; wf=wf3; CIN=128; COUT=256; co=bb-128; }
    else if (bb < 640) { w=w4; wf=wf4; CIN=256; COUT=256; co=bb-384; }
    else if (bb < 1152){ w=w5; wf=wf5; CIN=256; COUT=512; co=bb-640; }
    else               { w=w6; wf=wf6; CIN=512; COUT=512; co=bb-1152; }
    s8* sb = (s8*)smraw;
    int nf = CIN*9;
    const float* wb = w + (size_t)co*nf;
    for (int i = tid; i < nf; i += 256){
      float v = wb[i];
      sb[i] = (v > 0.f) ? (s8)1 : ((v < 0.f) ? (s8)-1 : (s8)0);
    }
    __syncthreads();
    int KK = CIN >> 5, CG = COUT >> 5;
    int cg = co >> 5, llo = co & 31;
    int items = 9*KK*2;                       // (tap, kk, kh) triples
    for (int it = tid; it < items; it += 256){
      int tap = it % 9; int r = it / 9;
      int kh = r & 1; int kk = r >> 1;
      u32 wd[4];
      #pragma unroll
      for (int q = 0; q < 4; q++){
        u32 v = 0;
        #pragma unroll
        for (int e = 0; e < 4; e++){
          unsigned char bch = (unsigned char)sb[(kk*32 + kh*16 + q*4 + e)*9 + tap];
          v |= ((u32)bch) << (8*e);
        }
        wd[q] = v;
      }
      size_t dstb = ((((size_t)tap*KK + kk)*CG + cg)*64 + (llo + kh*32))*16;
      uint4 st = { wd[0], wd[1], wd[2], wd[3] };
      *reinterpret_cast<uint4*>(wf + dstb) = st;
    }
  } else if (b < 4736){
    // ---------------- fc1 pack: k = c*16 + px, kw = px*16 + cw --------------
    int co = b - 3712;
    unsigned char* sb = (unsigned char*)smraw;
    const float* wb = fw1 + (size_t)co*8192;
    for (int i = tid; i < 8192; i += 256){
      float v = wb[i];
      sb[i] = (unsigned char)(((v != 0.f) ? 2u : 0u) | ((v > 0.f) ? 1u : 0u));
    }
    __syncthreads();
    int kw = tid;
    int px = kw >> 4, cw = kw & 15;
    u32 a = 0, s = 0;
    for (int j = 0; j < 32; j++){
      unsigned char bch = sb[(cw*32 + j)*16 + px];
      a |= (u32)(bch >> 1) << j;
      s |= (u32)(bch & 1u) << j;
    }
    size_t o = ((size_t)kw*1024 + co)*2;
    fw1p[o] = a; fw1p[o+1] = s;
  } else if (b < 5770){
    // ---------------- fw2 + fw3 bitplane pack -------------------------------
    int bb = b - 4736;
    const float* w; u32* wp; int COUT, co;
    if (bb < 1024){ w = fw2; wp = fw2p; COUT = 1024; co = bb; }
    else          { w = fw3; wp = fw3p; COUT = 10;   co = bb-1024; }
    unsigned char* sb = (unsigned char*)smraw;
    const float* wbp = w + (size_t)co*1024;
    for (int i = tid; i < 1024; i += 256){
      float v = wbp[i];
      sb[i] = (unsigned char)(((v != 0.f) ? 2u : 0u) | ((v > 0.f) ? 1u : 0u));
    }
    __syncthreads();
    for (int kw = tid; kw < 32; kw += 256){
      u32 a = 0, s = 0;
      for (int j = 0; j < 32; j++){
        unsigned char bch = sb[kw*32 + j];
        a |= (u32)(bch >> 1) << j;
        s |= (u32)(bch & 1u) << j;
      }
      size_t o = ((size_t)kw*COUT + co)*2;
      wp[o] = a; wp[o+1] = s;
    }
  } else {
    // ---------------- per-channel scales ------------------------------------
    int i = (b - 5770)*256 + tid;
    const float rs = __fdiv_rn(1.0f, __fsqrt_rn((float)(1.0 + 1e-5)));
    float v;
    if      (i < 128)  v = g1[i];
    else if (i < 256)  v = g2[i-128];
    else if (i < 512)  v = g3[i-256];
    else if (i < 768)  v = g4[i-512];
    else if (i < 1280) v = g5[i-768];
    else if (i < 1792) v = g6[i-1280];
    else if (i < 2816) v = gf1[i-1792];
    else if (i < 3840) v = gf2[i-2816];
    else if (i < 3850) v = gf3[i-3840];
    else return;
    scb[i] = __fmul_rn(v, rs);
  }
}

// ---------------------------------------------------------------------------
// MFMA ternary bconv: CGB=2, block-shared cout-group, per-tap B-slice staged
// global->LDS double-buffered. WPB=4 (r14/best config).
// ---------------------------------------------------------------------------
template<int CIN, int COUT, int H, int W, int POOL, int BITOUT, int WPB>
__global__ __launch_bounds__(WPB*64) void bconv_l(
    const s8* __restrict__ A, const s8* __restrict__ WF,
    const float* __restrict__ sc, const float* __restrict__ bt,
    s8* __restrict__ O, u32* __restrict__ OB){
  constexpr int KK = CIN/32, CG = COUT/32, CGB = 2;
  constexpr int XT = (W >= 16) ? 16 : 8;
  constexpr int YT = 32 / XT;
  constexpr int TPR = W / XT;
  constexpr int TROWS = H / YT;
  constexpr int NMT = 128*TROWS*TPR;
  constexpr int HO = POOL ? H/2 : H, WO = POOL ? W/2 : W;
  constexpr int RY = (XT == 16) ? 8 : 4;
  constexpr int TAPB = KK*CGB*1024;          // bytes per tap B-slice
  constexpr int NT = WPB*64;
  __shared__ s8 Bsh[2][TAPB];

  int tid = threadIdx.x, lane = tid & 63, wv = tid >> 6;
  int wid = blockIdx.x*WPB + wv;
  int mt = wid % NMT; int cb = wid / NMT;    // NMT%WPB==0 -> cb uniform/block
  int tx = mt % TPR; int r0 = mt / TPR;
  int ty = r0 % TROWS; int n = r0 / TROWS;
  int y0 = ty*YT, x0 = tx*XT;
  int p = lane & 31;
  int py = p / XT, px = p % XT;
  int y = y0 + py, x = x0 + px;
  int kh = lane >> 5;
  const s8* An = A + (size_t)n*H*W*CIN;

  auto stage = [&](int buf, int tap){
    const s8* src0 = WF + (((size_t)tap*KK)*CG + (size_t)cb*CGB)*1024;
    #pragma unroll
    for (int j = 0; j < TAPB/(NT*16); j++){
      int byte = (tid + j*NT)*16;
      int kk = byte / (CGB*1024);
      int rem = byte - kk*(CGB*1024);
      *reinterpret_cast<uint4*>(&Bsh[buf][byte]) =
        *reinterpret_cast<const uint4*>(src0 + (size_t)kk*CG*1024 + rem);
    }
  };

  i32x16 acc0 = {0,0,0,0,0,0,0,0,0,0,0,0,0,0,0,0};
  i32x16 acc1 = acc0;

  stage(0, 0);
  __syncthreads();
  int buf = 0;
  #pragma unroll
  for (int tap = 0; tap < 9; tap++){
    if (tap < 8) stage(buf^1, tap+1);        // overlap next-tap staging
    int dy = tap/3 - 1, dx = tap%3 - 1;
    int sy = y + dy, sx = x + dx;
    bool ok = ((unsigned)sy < (unsigned)H) && ((unsigned)sx < (unsigned)W);
    const s8* ap = An + ((size_t)sy*W + sx)*CIN + kh*16;
    #pragma unroll
    for (int kk = 0; kk < KK; kk++){
      i32x4 av = {0,0,0,0};
      if (ok) av = *reinterpret_cast<const i32x4*>(ap + kk*32);
      i32x4 b0 = *reinterpret_cast<const i32x4*>(&Bsh[buf][(kk*CGB+0)*1024 + lane*16]);
      i32x4 b1 = *reinterpret_cast<const i32x4*>(&Bsh[buf][(kk*CGB+1)*1024 + lane*16]);
      acc0 = __builtin_amdgcn_mfma_i32_32x32x32_i8(av, b0, acc0, 0, 0, 0);
      acc1 = __builtin_amdgcn_mfma_i32_32x32x32_i8(av, b1, acc1, 0, 0, 0);
    }
    __syncthreads();                          // staged writes visible
    buf ^= 1;
  }

  auto epi = [&](const i32x16& acc, int cgb){
    int co = (cb*CGB + cgb)*32 + (lane & 31);
    float ss = sc[co], bb = bt[co];
    if (POOL){
      #pragma unroll
      for (int q = 0; q < 4; q++){
        int rr = (q&1)*2 + (q>>1)*((XT == 16) ? 4 : 8);
        int z = max(max(acc[rr], acc[rr+1]), max(acc[rr+RY], acc[rr+RY+1]));
        float t = bn_ts((float)z, ss, bb);
        if (!BITOUT){
          int pb = (rr&3) + 8*(rr>>2) + 4*kh;
          int yy = y0 + pb/XT, xx2 = x0 + pb%XT;
          int oy = yy >> 1, ox = xx2 >> 1;
          O[(((size_t)n*HO + oy)*WO + ox)*COUT + co] = tsign(t);
        } else {
          u64 mP = __ballot(t > 0.f);
          u64 mN = __ballot(t < 0.f);
          if (lane == 0){
            u64 mA = mP | mN;
            int cw = cb*CGB + cgb;
            int pb0 = (rr&3) + 8*(rr>>2);
            int yy0 = y0 + pb0/XT, xx0 = x0 + pb0%XT;
            int p0 = (yy0>>1)*4 + (xx0>>1);
            int pb1 = pb0 + 4;
            int yy1 = y0 + pb1/XT, xx1 = x0 + pb1%XT;
            int p1 = (yy1>>1)*4 + (xx1>>1);
            size_t o0 = ((size_t)n*256 + p0*16 + cw)*2;
            size_t o1 = ((size_t)n*256 + p1*16 + cw)*2;
            OB[o0]   = (u32)mA;       OB[o0+1] = (u32)mP;
            OB[o1]   = (u32)(mA>>32); OB[o1+1] = (u32)(mP>>32);
          }
        }
      }
    } else {
      #pragma unroll
      for (int rr = 0; rr < 16; rr++){
        int pb = (rr&3) + 8*(rr>>2) + 4*kh;
        int yy = y0 + pb/XT, xx2 = x0 + pb%XT;
        float t = bn_ts((float)acc[rr], ss, bb);
        O[(((size_t)n*H + yy)*W + xx2)*COUT + co] = tsign(t);
      }
    }
  };
  epi(acc0, 0); epi(acc1, 1);
}

// ---------------------------------------------------------------------------
// Ternary FC + threshold + ternary ballot (bitplanes). (r14 separate kernels)
// ---------------------------------------------------------------------------
template<int KW>
__global__ __launch_bounds__(256) void fcb_k(
    const u32* __restrict__ A, const u32* __restrict__ Wp,
    const float* __restrict__ fb,
    const float* __restrict__ sc, const float* __restrict__ bt,
    u32* __restrict__ Op){
  int tid = threadIdx.x; int lane = tid & 63; int wv = tid >> 6;
  int wid = blockIdx.x*4 + wv;          // 128*16 waves
  int og = wid & 15; int n = wid >> 4;
  int o = og*64 + lane;
  const uint2* a = reinterpret_cast<const uint2*>(&A[(size_t)n*KW*2]);
  int z = 0;
  #pragma unroll 8
  for (int kw = 0; kw < KW; kw++){
    uint2 av = a[kw];
    uint2 wv_ = reinterpret_cast<const uint2*>(Wp)[kw*1024 + o];
    u32 v = av.x & wv_.x;
    u32 d = v & (av.y ^ wv_.y);
    z += __popc(v) - 2*__popc(d);
  }
  float vv = __fadd_rn((float)z, fb[o]);
  float t = bn_ts(vv, sc[o], bt[o]);
  u64 mP = __ballot(t > 0.f);
  u64 mN = __ballot(t < 0.f);
  if (lane == 0){
    int ob = (n*32 + og*2)*2;
    Op[ob]   = (u32)(mP | mN);
    Op[ob+1] = (u32)mP;
    Op[ob+2] = (u32)((mP | mN) >> 32);
    Op[ob+3] = (u32)(mP >> 32);
  }
}

// fc3 (10 outputs) + bn + log_softmax -> f32 out [128][10]
__global__ void fc3_k(const u32* __restrict__ A, const u32* __restrict__ Wp,
                      const float* __restrict__ fb,
                      const float* __restrict__ sc,
                      const float* __restrict__ bt,
                      float* __restrict__ out){
  int n = blockIdx.x; int lane = threadIdx.x;   // blockDim = 64
  __shared__ double ls[10];
  double t = 0.0;
  if (lane < 10){
    const uint2* a = reinterpret_cast<const uint2*>(&A[(size_t)n*32*2]);
    int z = 0;
    for (int kw = 0; kw < 32; kw++){
      uint2 av = a[kw];
      uint2 wv_ = reinterpret_cast<const uint2*>(Wp)[kw*10 + lane];
      u32 v = av.x & wv_.x;
      u32 d = v & (av.y ^ wv_.y);
      z += __popc(v) - 2*__popc(d);
    }
    float vv = __fadd_rn((float)z, fb[lane]);
    float tf = bn_ts(vv, sc[lane], bt[lane]);
    t = (double)tf;
    ls[lane] = t;
  }
  __syncthreads();
  if (lane < 10){
    double m = -1e300;
    for (int j = 0; j < 10; j++) m = fmax(m, ls[j]);
    double sum = 0.0;
    for (int j = 0; j < 10; j++) sum += exp(ls[j] - m);
    double r = t - m - log(sum);
    out[n*10 + lane] = (float)r;
  }
}

extern "C" void kernel_launch(void* const* d_in, const int* in_sizes, int n_in,
                              void* d_out, int out_size, void* d_ws, size_t ws_size,
                              hipStream_t stream){
  auto f = [&](int i){ return (const float*)d_in[i]; };
  const float *x  = f(0),  *w1 = f(1),  *c1b = f(2),
    *w2 = f(3),  *w3 = f(4),  *w4 = f(5),  *w5 = f(6),  *w6 = f(7),
    *fw1 = f(8), *fb1 = f(9), *fw2 = f(10), *fb2 = f(11),
    *fw3 = f(12), *fb3 = f(13),
    *g1 = f(14), *bt1 = f(15), *g2 = f(16), *bt2 = f(17),
    *g3 = f(18), *bt3 = f(19), *g4 = f(20), *bt4 = f(21),
    *g5 = f(22), *bt5 = f(23), *g6 = f(24), *bt6 = f(25),
    *gf1 = f(26), *btf1 = f(27), *gf2 = f(28), *btf2 = f(29),
    *gf3 = f(30), *btf3 = f(31);

  char* base = (char*)d_ws;
  size_t off = 0;
  auto alloc = [&](size_t bytes){ char* p = base + off; off += (bytes + 255) & ~(size_t)255; return p; };
  s8* poolA = (s8*)alloc(128ull*32*32*128);       // s1 / s3 / s5
  s8* poolB = (s8*)alloc(128ull*16*16*128);       // s2 / s4
  s8 *s1 = poolA, *s3 = poolA, *s5 = poolA;
  s8 *s2 = poolB, *s4 = poolB;
  s8 *wf2 = (s8*)alloc(9ull*128*128), *wf3 = (s8*)alloc(9ull*128*256),
     *wf4 = (s8*)alloc(9ull*256*256), *wf5 = (s8*)alloc(9ull*256*512),
     *wf6 = (s8*)alloc(9ull*512*512);
  u32 *wp1  = (u32*)alloc(385*4);                 // bitplanes + ctl + flag
  float* scb = (float*)alloc(3850*4);             // per-channel scales
  u32 *fw1p = (u32*)alloc(2ull*256*1024*4), *fw2p = (u32*)alloc(2ull*32*1024*4),
      *fw3p = (u32*)alloc(2ull*32*10*4);
  u32 *s6p  = (u32*)alloc(2ull*128*256*4);
  u32 *sf1  = (u32*)alloc(2ull*128*32*4), *sf2 = (u32*)alloc(2ull*128*32*4);

  float *sc2 = scb+128, *sc3 = scb+256, *sc4 = scb+512,
        *sc5 = scb+768, *sc6 = scb+1280, *scf1 = scb+1792, *scf2 = scb+2816,
        *scf3 = scb+3840;

  // dispatch 1: tiny w1 pack (conv1 in mega depends on it)
  pack_w1_k<<<1, 64, 0, stream>>>(w1, wp1);
  // dispatch 2: conv1 || all weight packing || scales
  mega_k<<<5786, 256, 0, stream>>>(
      x, wp1, c1b, g1, bt1, s1,
      w2, w3, w4, w5, w6, wf2, wf3, wf4, wf5, wf6,
      fw1, fw1p, fw2, fw3, fw2p, fw3p,
      g2, g3, g4, g5, g6, gf1, gf2, gf3, scb);

  // network — blocks = NMT*(CG/2)/WPB, WPB=4
  bconv_l<128,128,32,32,1,0,4><<<2048, 256, 0, stream>>>(s1, wf2, sc2, bt2, s2, nullptr);
  bconv_l<128,256,16,16,0,0,4><<<1024, 256, 0, stream>>>(s2, wf3, sc3, bt3, s3, nullptr);
  bconv_l<256,256,16,16,1,0,4><<<1024, 256, 0, stream>>>(s3, wf4, sc4, bt4, s4, nullptr);
  bconv_l<256,512, 8, 8,0,0,4><<< 512, 256, 0, stream>>>(s4, wf5, sc5, bt5, s5, nullptr);
  bconv_l<512,512, 8, 8,1,1,4><<< 512, 256, 0, stream>>>(s5, wf6, sc6, bt6, nullptr, s6p);
  fcb_k<256><<<(128*16)/4, 256, 0, stream>>>(s6p, fw1p, fb1, scf1, btf1, sf1);
  fcb_k<32><<<(128*16)/4,  256, 0, stream>>>(sf1, fw2p, fb2, scf2, btf2, sf2);
  fc3_k<<<128, 64, 0, stream>>>(sf2, fw3p, fb3, scf3, btf3, (float*)d_out);
}

// Round 19
// 285.770 us; speedup vs baseline: 1.2409x; 1.0029x over previous
//
#include <hip/hip_runtime.h>
#include <hip/hip_bf16.h>

using u32 = unsigned int;
using u64 = unsigned long long;
using s8  = signed char;
typedef int i32x4  __attribute__((ext_vector_type(4)));
typedef int i32x16 __attribute__((ext_vector_type(16)));

__device__ __forceinline__ s8 tsign(float t){
  return (t > 0.f) ? (s8)1 : ((t < 0.f) ? (s8)-1 : (s8)0);
}
// threshold with precomputed scale: t = fl(fl(z*sc)+b) — identical roundings
__device__ __forceinline__ float bn_ts(float z, float sc, float b){
  return __fadd_rn(__fmul_rn(z, sc), b);
}

// ---------------------------------------------------------------------------
// w1 pack: bitplanes [co*2..], one ctl word per co at [256+co], flag at [384]
// ---------------------------------------------------------------------------
__global__ void pack_w1_k(const float* __restrict__ w1, u32* __restrict__ wp1){
  int lane = threadIdx.x;                 // one wave of 64
  bool hz = false;
  for (int h = 0; h < 2; h++){
    int co = h*64 + lane;
    u32 a = 0, s = 0, ctlw = 0;
    for (int tap = 0; tap < 9; tap++){
      float v0 = w1[(co*3 + 0)*9 + tap];
      float v1 = w1[(co*3 + 1)*9 + tap];
      float v2 = w1[(co*3 + 2)*9 + tap];
      int b0 = tap*3;
      a |= ((v0 != 0.f) ? 1u : 0u) << b0;     s |= ((v0 > 0.f) ? 1u : 0u) << b0;
      a |= ((v1 != 0.f) ? 1u : 0u) << (b0+1); s |= ((v1 > 0.f) ? 1u : 0u) << (b0+1);
      a |= ((v2 != 0.f) ? 1u : 0u) << (b0+2); s |= ((v2 > 0.f) ? 1u : 0u) << (b0+2);
      hz |= (v0 == 0.f) || (v1 == 0.f) || (v2 == 0.f);
      u32 f = (((v0 > 0.f) == (v1 > 0.f)) ? 1u : 0u)
            | ((v0 < 0.f) ? 2u : 0u)
            | ((v2 < 0.f) ? 4u : 0u);
      ctlw |= f << b0;
    }
    wp1[co*2]   = a;
    wp1[co*2+1] = s;
    wp1[256 + co] = ctlw;
  }
  u64 m = __ballot(hz);
  if (lane == 0) wp1[384] = (m != 0ull) ? 1u : 0u;
}

// ---------------------------------------------------------------------------
// MEGA prep+conv1 kernel (r18, unchanged).
// ---------------------------------------------------------------------------
__global__ __launch_bounds__(256) void mega_k(
    const float* __restrict__ x, const u32* __restrict__ wp1,
    const float* __restrict__ c1b, const float* __restrict__ g1,
    const float* __restrict__ bt1, s8* __restrict__ s1,
    const float* __restrict__ w2, const float* __restrict__ w3,
    const float* __restrict__ w4, const float* __restrict__ w5,
    const float* __restrict__ w6,
    s8* __restrict__ wf2, s8* __restrict__ wf3, s8* __restrict__ wf4,
    s8* __restrict__ wf5, s8* __restrict__ wf6,
    const float* __restrict__ fw1, u32* __restrict__ fw1p,
    const float* __restrict__ fw2, const float* __restrict__ fw3,
    u32* __restrict__ fw2p, u32* __restrict__ fw3p,
    const float* __restrict__ g2, const float* __restrict__ g3,
    const float* __restrict__ g4, const float* __restrict__ g5,
    const float* __restrict__ g6, const float* __restrict__ gf1,
    const float* __restrict__ gf2, const float* __restrict__ gf3,
    float* __restrict__ scb){
  __shared__ char smraw[8192];
  int b = blockIdx.x, tid = threadIdx.x;

  if (b < 2048){
    // ---------------- conv1 (r14): 32 couts/wave ---------------------------
    int lane = tid & 63, wv = tid >> 6;
    int wid = b*4 + wv;              // 8192 waves: [n(128)][chunk(16)][coh(4)]
    int coh = wid & 3;
    int chunk = (wid >> 2) & 15;
    int n = wid >> 6;
    int py = lane >> 5, px = lane & 31;
    int y = chunk*2 + py;
    const float* xb = x + (size_t)n*3*1024;
    const float rs = __fdiv_rn(1.0f, __fsqrt_rn((float)(1.0 + 1e-5)));

    float xv[3][9];
    #pragma unroll
    for (int ci = 0; ci < 3; ci++)
      #pragma unroll
      for (int tap = 0; tap < 9; tap++){
        int yy = y + tap/3 - 1, xx = px + tap%3 - 1;
        bool ok = ((unsigned)yy < 32u) && ((unsigned)xx < 32u);
        xv[ci][tap] = ok ? xb[(ci*32 + yy)*32 + xx] : 0.f;
      }
    float pc0[9], pc1[9];
    #pragma unroll
    for (int tap = 0; tap < 9; tap++){
      pc0[tap] = __fadd_rn(xv[0][tap], xv[1][tap]);
      pc1[tap] = __fadd_rn(xv[0][tap], -xv[1][tap]);
    }

    size_t pixbase = (((size_t)n*1024) + y*32 + px)*128 + coh*32;
    bool fallback = (wp1[384] != 0u);

    if (!fallback){
      for (int co4 = 0; co4 < 32; co4 += 4){
        u32 outw = 0;
        #pragma unroll
        for (int j = 0; j < 4; j++){
          int co = coh*32 + co4 + j;
          u32 ctlw = wp1[256 + co];          // wave-uniform
          float acc = 0.f;
          #pragma unroll
          for (int tap = 0; tap < 9; tap++){
            u32 f = ctlw >> (3*tap);
            float s01 = (f & 1u) ? pc0[tap] : pc1[tap];
            s01 = __uint_as_float(__float_as_uint(s01) ^ ((f & 2u) << 30));
            float t2 = __uint_as_float(__float_as_uint(xv[2][tap]) ^ ((f & 4u) << 29));
            acc = __fadd_rn(acc, __fadd_rn(s01, t2));
          }
          float v = __fadd_rn(acc, c1b[co]);
          float t = bn_ts(v, __fmul_rn(g1[co], rs), bt1[co]);
          outw |= ((u32)(unsigned char)tsign(t)) << (8*j);
        }
        *reinterpret_cast<u32*>(&s1[pixbase + co4]) = outw;
      }
    } else {
      for (int co4 = 0; co4 < 32; co4 += 4){
        u32 outw = 0;
        #pragma unroll
        for (int j = 0; j < 4; j++){
          int co = coh*32 + co4 + j;
          u32 wA = wp1[co*2], wS = wp1[co*2+1];
          float acc = 0.f;
          #pragma unroll
          for (int tap = 0; tap < 9; tap++){
            float pt = 0.f;
            #pragma unroll
            for (int ci = 0; ci < 3; ci++){
              int bit = tap*3 + ci;
              float sg = ((wA >> bit) & 1u) ? (((wS >> bit) & 1u) ? 1.f : -1.f) : 0.f;
              pt = __fadd_rn(pt, __fmul_rn(sg, xv[ci][tap]));
            }
            acc = __fadd_rn(acc, pt);
          }
          float v = __fadd_rn(acc, c1b[co]);
          float t = bn_ts(v, __fmul_rn(g1[co], rs), bt1[co]);
          outw |= ((u32)(unsigned char)tsign(t)) << (8*j);
        }
        *reinterpret_cast<u32*>(&s1[pixbase + co4]) = outw;
      }
    }
  } else if (b < 3712){
    // -------- conv-weight MFMA fragment pack, vectorized uint4 stores ------
    int bb = b - 2048;
    const float* w; s8* wf; int CIN, COUT, co;
    if      (bb < 128) { w=w2; wf=wf2; CIN=128; COUT=128; co=bb; }
    else if (bb < 384) { w=w3; wf=wf3; CIN=128; COUT=256; co=bb-128; }
    else if (bb < 640) { w=w4; wf=wf4; CIN=256; COUT=256; co=bb-384; }
    else if (bb < 1152){ w=w5; wf=wf5; CIN=256; COUT=512; co=bb-640; }
    else               { w=w6; wf=wf6; CIN=512; COUT=512; co=bb-1152; }
    s8* sb = (s8*)smraw;
    int nf = CIN*9;
    const float* wb = w + (size_t)co*nf;
    for (int i = tid; i < nf; i += 256){
      float v = wb[i];
      sb[i] = (v > 0.f) ? (s8)1 : ((v < 0.f) ? (s8)-1 : (s8)0);
    }
    __syncthreads();
    int KK = CIN >> 5, CG = COUT >> 5;
    int cg = co >> 5, llo = co & 31;
    int items = 9*KK*2;                       // (tap, kk, kh) triples
    for (int it = tid; it < items; it += 256){
      int tap = it % 9; int r = it / 9;
      int kh = r & 1; int kk = r >> 1;
      u32 wd[4];
      #pragma unroll
      for (int q = 0; q < 4; q++){
        u32 v = 0;
        #pragma unroll
        for (int e = 0; e < 4; e++){
          unsigned char bch = (unsigned char)sb[(kk*32 + kh*16 + q*4 + e)*9 + tap];
          v |= ((u32)bch) << (8*e);
        }
        wd[q] = v;
      }
      size_t dstb = ((((size_t)tap*KK + kk)*CG + cg)*64 + (llo + kh*32))*16;
      uint4 st = { wd[0], wd[1], wd[2], wd[3] };
      *reinterpret_cast<uint4*>(wf + dstb) = st;
    }
  } else if (b < 4736){
    // ---------------- fc1 pack: k = c*16 + px, kw = px*16 + cw --------------
    int co = b - 3712;
    unsigned char* sb = (unsigned char*)smraw;
    const float* wb = fw1 + (size_t)co*8192;
    for (int i = tid; i < 8192; i += 256){
      float v = wb[i];
      sb[i] = (unsigned char)(((v != 0.f) ? 2u : 0u) | ((v > 0.f) ? 1u : 0u));
    }
    __syncthreads();
    int kw = tid;
    int px = kw >> 4, cw = kw & 15;
    u32 a = 0, s = 0;
    for (int j = 0; j < 32; j++){
      unsigned char bch = sb[(cw*32 + j)*16 + px];
      a |= (u32)(bch >> 1) << j;
      s |= (u32)(bch & 1u) << j;
    }
    size_t o = ((size_t)kw*1024 + co)*2;
    fw1p[o] = a; fw1p[o+1] = s;
  } else if (b < 5770){
    // ---------------- fw2 + fw3 bitplane pack -------------------------------
    int bb = b - 4736;
    const float* w; u32* wp; int COUT, co;
    if (bb < 1024){ w = fw2; wp = fw2p; COUT = 1024; co = bb; }
    else          { w = fw3; wp = fw3p; COUT = 10;   co = bb-1024; }
    unsigned char* sb = (unsigned char*)smraw;
    const float* wbp = w + (size_t)co*1024;
    for (int i = tid; i < 1024; i += 256){
      float v = wbp[i];
      sb[i] = (unsigned char)(((v != 0.f) ? 2u : 0u) | ((v > 0.f) ? 1u : 0u));
    }
    __syncthreads();
    for (int kw = tid; kw < 32; kw += 256){
      u32 a = 0, s = 0;
      for (int j = 0; j < 32; j++){
        unsigned char bch = sb[kw*32 + j];
        a |= (u32)(bch >> 1) << j;
        s |= (u32)(bch & 1u) << j;
      }
      size_t o = ((size_t)kw*COUT + co)*2;
      wp[o] = a; wp[o+1] = s;
    }
  } else {
    // ---------------- per-channel scales ------------------------------------
    int i = (b - 5770)*256 + tid;
    const float rs = __fdiv_rn(1.0f, __fsqrt_rn((float)(1.0 + 1e-5)));
    float v;
    if      (i < 128)  v = g1[i];
    else if (i < 256)  v = g2[i-128];
    else if (i < 512)  v = g3[i-256];
    else if (i < 768)  v = g4[i-512];
    else if (i < 1280) v = g5[i-768];
    else if (i < 1792) v = g6[i-1280];
    else if (i < 2816) v = gf1[i-1792];
    else if (i < 3840) v = gf2[i-2816];
    else if (i < 3850) v = gf3[i-3840];
    else return;
    scb[i] = __fmul_rn(v, rs);
  }
}

// ---------------------------------------------------------------------------
// MFMA ternary bconv: CGB=2, block-shared cout-group, per-tap B-slice staged
// global->LDS double-buffered. PT = pixel tiles per wave: one pair of B
// ds_reads feeds 2*PT MFMAs (PT=2 turns the kk-step from LDS-bound into
// MFMA-bound). PT=2 only where wave count stays >= 8/CU (b2/b3/b4).
// ---------------------------------------------------------------------------
template<int CIN, int COUT, int H, int W, int POOL, int BITOUT, int WPB, int PT>
__global__ __launch_bounds__(WPB*64) void bconv_l(
    const s8* __restrict__ A, const s8* __restrict__ WF,
    const float* __restrict__ sc, const float* __restrict__ bt,
    s8* __restrict__ O, u32* __restrict__ OB){
  constexpr int KK = CIN/32, CG = COUT/32, CGB = 2;
  constexpr int XT = (W >= 16) ? 16 : 8;
  constexpr int YT = 32 / XT;
  constexpr int TPR = W / XT;
  constexpr int TROWS = H / YT;
  constexpr int NMT = 128*TROWS*TPR;
  constexpr int NTG = NMT / PT;              // tile-groups (1 group / wave)
  constexpr int HO = POOL ? H/2 : H, WO = POOL ? W/2 : W;
  constexpr int RY = (XT == 16) ? 8 : 4;
  constexpr int TAPB = KK*CGB*1024;          // bytes per tap B-slice
  constexpr int NT = WPB*64;
  __shared__ s8 Bsh[2][TAPB];

  int tid = threadIdx.x, lane = tid & 63, wv = tid >> 6;
  int wid = blockIdx.x*WPB + wv;
  int mtg = wid % NTG; int cb = wid / NTG;   // NTG%WPB==0 -> cb uniform/block
  int p = lane & 31;
  int py = p / XT, px = p % XT;
  int kh = lane >> 5;

  // per-tile coordinates
  int y0t[PT], x0t[PT], nt[PT];
  #pragma unroll
  for (int t = 0; t < PT; t++){
    int mt = mtg*PT + t;
    int tx = mt % TPR; int r0 = mt / TPR;
    int ty = r0 % TROWS; nt[t] = r0 / TROWS;
    y0t[t] = ty*YT; x0t[t] = tx*XT;
  }

  auto stage = [&](int buf, int tap){
    const s8* src0 = WF + (((size_t)tap*KK)*CG + (size_t)cb*CGB)*1024;
    #pragma unroll
    for (int j = 0; j < TAPB/(NT*16); j++){
      int byte = (tid + j*NT)*16;
      int kk = byte / (CGB*1024);
      int rem = byte - kk*(CGB*1024);
      *reinterpret_cast<uint4*>(&Bsh[buf][byte]) =
        *reinterpret_cast<const uint4*>(src0 + (size_t)kk*CG*1024 + rem);
    }
  };

  i32x16 accA0 = {0,0,0,0,0,0,0,0,0,0,0,0,0,0,0,0};
  i32x16 accA1 = accA0, accB0 = accA0, accB1 = accA0;

  stage(0, 0);
  __syncthreads();
  int buf = 0;
  #pragma unroll
  for (int tap = 0; tap < 9; tap++){
    if (tap < 8) stage(buf^1, tap+1);        // overlap next-tap staging
    int dy = tap/3 - 1, dx = tap%3 - 1;
    // tile A addresses
    int syA = y0t[0] + py + dy, sxA = x0t[0] + px + dx;
    bool okA = ((unsigned)syA < (unsigned)H) && ((unsigned)sxA < (unsigned)W);
    const s8* apA = A + (((size_t)nt[0]*H + syA)*W + sxA)*CIN + kh*16;
    const s8* apB = nullptr; bool okB = false;
    if (PT == 2){
      int syB = y0t[1] + py + dy, sxB = x0t[1] + px + dx;
      okB = ((unsigned)syB < (unsigned)H) && ((unsigned)sxB < (unsigned)W);
      apB = A + (((size_t)nt[1]*H + syB)*W + sxB)*CIN + kh*16;
    }
    #pragma unroll
    for (int kk = 0; kk < KK; kk++){
      i32x4 avA = {0,0,0,0};
      if (okA) avA = *reinterpret_cast<const i32x4*>(apA + kk*32);
      i32x4 b0 = *reinterpret_cast<const i32x4*>(&Bsh[buf][(kk*CGB+0)*1024 + lane*16]);
      i32x4 b1 = *reinterpret_cast<const i32x4*>(&Bsh[buf][(kk*CGB+1)*1024 + lane*16]);
      accA0 = __builtin_amdgcn_mfma_i32_32x32x32_i8(avA, b0, accA0, 0, 0, 0);
      accA1 = __builtin_amdgcn_mfma_i32_32x32x32_i8(avA, b1, accA1, 0, 0, 0);
      if (PT == 2){
        i32x4 avB = {0,0,0,0};
        if (okB) avB = *reinterpret_cast<const i32x4*>(apB + kk*32);
        accB0 = __builtin_amdgcn_mfma_i32_32x32x32_i8(avB, b0, accB0, 0, 0, 0);
        accB1 = __builtin_amdgcn_mfma_i32_32x32x32_i8(avB, b1, accB1, 0, 0, 0);
      }
    }
    __syncthreads();                          // staged writes visible
    buf ^= 1;
  }

  auto epi = [&](const i32x16& acc, int cgb, int y0, int x0, int n){
    int co = (cb*CGB + cgb)*32 + (lane & 31);
    float ss = sc[co], bb = bt[co];
    if (POOL){
      #pragma unroll
      for (int q = 0; q < 4; q++){
        int rr = (q&1)*2 + (q>>1)*((XT == 16) ? 4 : 8);
        int z = max(max(acc[rr], acc[rr+1]), max(acc[rr+RY], acc[rr+RY+1]));
        float t = bn_ts((float)z, ss, bb);
        if (!BITOUT){
          int pb = (rr&3) + 8*(rr>>2) + 4*kh;
          int yy = y0 + pb/XT, xx2 = x0 + pb%XT;
          int oy = yy >> 1, ox = xx2 >> 1;
          O[(((size_t)n*HO + oy)*WO + ox)*COUT + co] = tsign(t);
        } else {
          u64 mP = __ballot(t > 0.f);
          u64 mN = __ballot(t < 0.f);
          if (lane == 0){
            u64 mA = mP | mN;
            int cw = cb*CGB + cgb;
            int pb0 = (rr&3) + 8*(rr>>2);
            int yy0 = y0 + pb0/XT, xx0 = x0 + pb0%XT;
            int p0 = (yy0>>1)*4 + (xx0>>1);
            int pb1 = pb0 + 4;
            int yy1 = y0 + pb1/XT, xx1 = x0 + pb1%XT;
            int p1 = (yy1>>1)*4 + (xx1>>1);
            size_t o0 = ((size_t)n*256 + p0*16 + cw)*2;
            size_t o1 = ((size_t)n*256 + p1*16 + cw)*2;
            OB[o0]   = (u32)mA;       OB[o0+1] = (u32)mP;
            OB[o1]   = (u32)(mA>>32); OB[o1+1] = (u32)(mP>>32);
          }
        }
      }
    } else {
      #pragma unroll
      for (int rr = 0; rr < 16; rr++){
        int pb = (rr&3) + 8*(rr>>2) + 4*kh;
        int yy = y0 + pb/XT, xx2 = x0 + pb%XT;
        float t = bn_ts((float)acc[rr], ss, bb);
        O[(((size_t)n*H + yy)*W + xx2)*COUT + co] = tsign(t);
      }
    }
  };
  epi(accA0, 0, y0t[0], x0t[0], nt[0]);
  epi(accA1, 1, y0t[0], x0t[0], nt[0]);
  if (PT == 2){
    epi(accB0, 0, y0t[1], x0t[1], nt[1]);
    epi(accB1, 1, y0t[1], x0t[1], nt[1]);
  }
}

// ---------------------------------------------------------------------------
// Ternary FC + threshold + ternary ballot (bitplanes).
// ---------------------------------------------------------------------------
template<int KW>
__global__ __launch_bounds__(256) void fcb_k(
    const u32* __restrict__ A, const u32* __restrict__ Wp,
    const float* __restrict__ fb,
    const float* __restrict__ sc, const float* __restrict__ bt,
    u32* __restrict__ Op){
  int tid = threadIdx.x; int lane = tid & 63; int wv = tid >> 6;
  int wid = blockIdx.x*4 + wv;          // 128*16 waves
  int og = wid & 15; int n = wid >> 4;
  int o = og*64 + lane;
  const uint2* a = reinterpret_cast<const uint2*>(&A[(size_t)n*KW*2]);
  int z = 0;
  #pragma unroll 8
  for (int kw = 0; kw < KW; kw++){
    uint2 av = a[kw];
    uint2 wv_ = reinterpret_cast<const uint2*>(Wp)[kw*1024 + o];
    u32 v = av.x & wv_.x;
    u32 d = v & (av.y ^ wv_.y);
    z += __popc(v) - 2*__popc(d);
  }
  float vv = __fadd_rn((float)z, fb[o]);
  float t = bn_ts(vv, sc[o], bt[o]);
  u64 mP = __ballot(t > 0.f);
  u64 mN = __ballot(t < 0.f);
  if (lane == 0){
    int ob = (n*32 + og*2)*2;
    Op[ob]   = (u32)(mP | mN);
    Op[ob+1] = (u32)mP;
    Op[ob+2] = (u32)((mP | mN) >> 32);
    Op[ob+3] = (u32)(mP >> 32);
  }
}

// fc3 (10 outputs) + bn + log_softmax -> f32 out [128][10]
__global__ void fc3_k(const u32* __restrict__ A, const u32* __restrict__ Wp,
                      const float* __restrict__ fb,
                      const float* __restrict__ sc,
                      const float* __restrict__ bt,
                      float* __restrict__ out){
  int n = blockIdx.x; int lane = threadIdx.x;   // blockDim = 64
  __shared__ double ls[10];
  double t = 0.0;
  if (lane < 10){
    const uint2* a = reinterpret_cast<const uint2*>(&A[(size_t)n*32*2]);
    int z = 0;
    for (int kw = 0; kw < 32; kw++){
      uint2 av = a[kw];
      uint2 wv_ = reinterpret_cast<const uint2*>(Wp)[kw*10 + lane];
      u32 v = av.x & wv_.x;
      u32 d = v & (av.y ^ wv_.y);
      z += __popc(v) - 2*__popc(d);
    }
    float vv = __fadd_rn((float)z, fb[lane]);
    float tf = bn_ts(vv, sc[lane], bt[lane]);
    t = (double)tf;
    ls[lane] = t;
  }
  __syncthreads();
  if (lane < 10){
    double m = -1e300;
    for (int j = 0; j < 10; j++) m = fmax(m, ls[j]);
    double sum = 0.0;
    for (int j = 0; j < 10; j++) sum += exp(ls[j] - m);
    double r = t - m - log(sum);
    out[n*10 + lane] = (float)r;
  }
}

extern "C" void kernel_launch(void* const* d_in, const int* in_sizes, int n_in,
                              void* d_out, int out_size, void* d_ws, size_t ws_size,
                              hipStream_t stream){
  auto f = [&](int i){ return (const float*)d_in[i]; };
  const float *x  = f(0),  *w1 = f(1),  *c1b = f(2),
    *w2 = f(3),  *w3 = f(4),  *w4 = f(5),  *w5 = f(6),  *w6 = f(7),
    *fw1 = f(8), *fb1 = f(9), *fw2 = f(10), *fb2 = f(11),
    *fw3 = f(12), *fb3 = f(13),
    *g1 = f(14), *bt1 = f(15), *g2 = f(16), *bt2 = f(17),
    *g3 = f(18), *bt3 = f(19), *g4 = f(20), *bt4 = f(21),
    *g5 = f(22), *bt5 = f(23), *g6 = f(24), *bt6 = f(25),
    *gf1 = f(26), *btf1 = f(27), *gf2 = f(28), *btf2 = f(29),
    *gf3 = f(30), *btf3 = f(31);

  char* base = (char*)d_ws;
  size_t off = 0;
  auto alloc = [&](size_t bytes){ char* p = base + off; off += (bytes + 255) & ~(size_t)255; return p; };
  s8* poolA = (s8*)alloc(128ull*32*32*128);       // s1 / s3 / s5
  s8* poolB = (s8*)alloc(128ull*16*16*128);       // s2 / s4
  s8 *s1 = poolA, *s3 = poolA, *s5 = poolA;
  s8 *s2 = poolB, *s4 = poolB;
  s8 *wf2 = (s8*)alloc(9ull*128*128), *wf3 = (s8*)alloc(9ull*128*256),
     *wf4 = (s8*)alloc(9ull*256*256), *wf5 = (s8*)alloc(9ull*256*512),
     *wf6 = (s8*)alloc(9ull*512*512);
  u32 *wp1  = (u32*)alloc(385*4);                 // bitplanes + ctl + flag
  float* scb = (float*)alloc(3850*4);             // per-channel scales
  u32 *fw1p = (u32*)alloc(2ull*256*1024*4), *fw2p = (u32*)alloc(2ull*32*1024*4),
      *fw3p = (u32*)alloc(2ull*32*10*4);
  u32 *s6p  = (u32*)alloc(2ull*128*256*4);
  u32 *sf1  = (u32*)alloc(2ull*128*32*4), *sf2 = (u32*)alloc(2ull*128*32*4);

  float *sc2 = scb+128, *sc3 = scb+256, *sc4 = scb+512,
        *sc5 = scb+768, *sc6 = scb+1280, *scf1 = scb+1792, *scf2 = scb+2816,
        *scf3 = scb+3840;

  // dispatch 1: tiny w1 pack (conv1 in mega depends on it)
  pack_w1_k<<<1, 64, 0, stream>>>(w1, wp1);
  // dispatch 2: conv1 || all weight packing || scales
  mega_k<<<5786, 256, 0, stream>>>(
      x, wp1, c1b, g1, bt1, s1,
      w2, w3, w4, w5, w6, wf2, wf3, wf4, wf5, wf6,
      fw1, fw1p, fw2, fw3, fw2p, fw3p,
      g2, g3, g4, g5, g6, gf1, gf2, gf3, scb);

  // network — blocks = NTG*(CG/2)/WPB
  bconv_l<128,128,32,32,1,0,4,2><<<1024, 256, 0, stream>>>(s1, wf2, sc2, bt2, s2, nullptr);
  bconv_l<128,256,16,16,0,0,4,2><<< 512, 256, 0, stream>>>(s2, wf3, sc3, bt3, s3, nullptr);
  bconv_l<256,256,16,16,1,0,4,2><<< 512, 256, 0, stream>>>(s3, wf4, sc4, bt4, s4, nullptr);
  bconv_l<256,512, 8, 8,0,0,4,1><<< 512, 256, 0, stream>>>(s4, wf5, sc5, bt5, s5, nullptr);
  bconv_l<512,512, 8, 8,1,1,4,1><<< 512, 256, 0, stream>>>(s5, wf6, sc6, bt6, nullptr, s6p);
  fcb_k<256><<<(128*16)/4, 256, 0, stream>>>(s6p, fw1p, fb1, scf1, btf1, sf1);
  fcb_k<32><<<(128*16)/4,  256, 0, stream>>>(sf1, fw2p, fb2, scf2, btf2, sf2);
  fc3_k<<<128, 64, 0, stream>>>(sf2, fw3p, fb3, scf3, btf3, (float*)d_out);
}

// Round 20
// 285.059 us; speedup vs baseline: 1.2440x; 1.0025x over previous
//
#include <hip/hip_runtime.h>
#include <hip/hip_bf16.h>

using u32 = unsigned int;
using u64 = unsigned long long;
using s8  = signed char;
typedef int i32x4  __attribute__((ext_vector_type(4)));
typedef int i32x16 __attribute__((ext_vector_type(16)));

__device__ __forceinline__ s8 tsign(float t){
  return (t > 0.f) ? (s8)1 : ((t < 0.f) ? (s8)-1 : (s8)0);
}
// threshold with precomputed scale: t = fl(fl(z*sc)+b) — identical roundings
__device__ __forceinline__ float bn_ts(float z, float sc, float b){
  return __fadd_rn(__fmul_rn(z, sc), b);
}
// ternary sign byte for MFMA fragments
__device__ __forceinline__ u32 enc_sign(float v){
  return (u32)(unsigned char)((v > 0.f) ? (s8)1 : ((v < 0.f) ? (s8)-1 : (s8)0));
}
// bitplane byte: bit1 = (v!=0), bit0 = (v>0)
__device__ __forceinline__ u32 enc_bch(float v){
  return ((v != 0.f) ? 2u : 0u) | ((v > 0.f) ? 1u : 0u);
}

// ---------------------------------------------------------------------------
// w1 pack: bitplanes [co*2..], one ctl word per co at [256+co], flag at [384]
// ---------------------------------------------------------------------------
__global__ void pack_w1_k(const float* __restrict__ w1, u32* __restrict__ wp1){
  int lane = threadIdx.x;                 // one wave of 64
  bool hz = false;
  for (int h = 0; h < 2; h++){
    int co = h*64 + lane;
    u32 a = 0, s = 0, ctlw = 0;
    for (int tap = 0; tap < 9; tap++){
      float v0 = w1[(co*3 + 0)*9 + tap];
      float v1 = w1[(co*3 + 1)*9 + tap];
      float v2 = w1[(co*3 + 2)*9 + tap];
      int b0 = tap*3;
      a |= ((v0 != 0.f) ? 1u : 0u) << b0;     s |= ((v0 > 0.f) ? 1u : 0u) << b0;
      a |= ((v1 != 0.f) ? 1u : 0u) << (b0+1); s |= ((v1 > 0.f) ? 1u : 0u) << (b0+1);
      a |= ((v2 != 0.f) ? 1u : 0u) << (b0+2); s |= ((v2 > 0.f) ? 1u : 0u) << (b0+2);
      hz |= (v0 == 0.f) || (v1 == 0.f) || (v2 == 0.f);
      u32 f = (((v0 > 0.f) == (v1 > 0.f)) ? 1u : 0u)
            | ((v0 < 0.f) ? 2u : 0u)
            | ((v2 < 0.f) ? 4u : 0u);
      ctlw |= f << b0;
    }
    wp1[co*2]   = a;
    wp1[co*2+1] = s;
    wp1[256 + co] = ctlw;
  }
  u64 m = __ballot(hz);
  if (lane == 0) wp1[384] = (m != 0ull) ? 1u : 0u;
}

// ---------------------------------------------------------------------------
// MEGA prep+conv1 kernel. Pack sections now use float4 loads (16 B/lane).
// Block ranges:
//   [0,2048)      conv1 (r14 version: 32 couts/wave)
//   [2048,3712)   conv-weight MFMA fragment pack (w2..w6)
//   [3712,4736)   fc1 weight pack (K-permuted bitplanes)
//   [4736,5770)   fw2+fw3 bitplane pack
//   [5770,5786)   per-channel scales
// ---------------------------------------------------------------------------
__global__ __launch_bounds__(256) void mega_k(
    const float* __restrict__ x, const u32* __restrict__ wp1,
    const float* __restrict__ c1b, const float* __restrict__ g1,
    const float* __restrict__ bt1, s8* __restrict__ s1,
    const float* __restrict__ w2, const float* __restrict__ w3,
    const float* __restrict__ w4, const float* __restrict__ w5,
    const float* __restrict__ w6,
    s8* __restrict__ wf2, s8* __restrict__ wf3, s8* __restrict__ wf4,
    s8* __restrict__ wf5, s8* __restrict__ wf6,
    const float* __restrict__ fw1, u32* __restrict__ fw1p,
    const float* __restrict__ fw2, const float* __restrict__ fw3,
    u32* __restrict__ fw2p, u32* __restrict__ fw3p,
    const float* __restrict__ g2, const float* __restrict__ g3,
    const float* __restrict__ g4, const float* __restrict__ g5,
    const float* __restrict__ g6, const float* __restrict__ gf1,
    const float* __restrict__ gf2, const float* __restrict__ gf3,
    float* __restrict__ scb){
  __shared__ char smraw[8192];
  int b = blockIdx.x, tid = threadIdx.x;

  if (b < 2048){
    // ---------------- conv1 (r14): 32 couts/wave ---------------------------
    int lane = tid & 63, wv = tid >> 6;
    int wid = b*4 + wv;              // 8192 waves: [n(128)][chunk(16)][coh(4)]
    int coh = wid & 3;
    int chunk = (wid >> 2) & 15;
    int n = wid >> 6;
    int py = lane >> 5, px = lane & 31;
    int y = chunk*2 + py;
    const float* xb = x + (size_t)n*3*1024;
    const float rs = __fdiv_rn(1.0f, __fsqrt_rn((float)(1.0 + 1e-5)));

    float xv[3][9];
    #pragma unroll
    for (int ci = 0; ci < 3; ci++)
      #pragma unroll
      for (int tap = 0; tap < 9; tap++){
        int yy = y + tap/3 - 1, xx = px + tap%3 - 1;
        bool ok = ((unsigned)yy < 32u) && ((unsigned)xx < 32u);
        xv[ci][tap] = ok ? xb[(ci*32 + yy)*32 + xx] : 0.f;
      }
    float pc0[9], pc1[9];
    #pragma unroll
    for (int tap = 0; tap < 9; tap++){
      pc0[tap] = __fadd_rn(xv[0][tap], xv[1][tap]);
      pc1[tap] = __fadd_rn(xv[0][tap], -xv[1][tap]);
    }

    size_t pixbase = (((size_t)n*1024) + y*32 + px)*128 + coh*32;
    bool fallback = (wp1[384] != 0u);

    if (!fallback){
      for (int co4 = 0; co4 < 32; co4 += 4){
        u32 outw = 0;
        #pragma unroll
        for (int j = 0; j < 4; j++){
          int co = coh*32 + co4 + j;
          u32 ctlw = wp1[256 + co];          // wave-uniform
          float acc = 0.f;
          #pragma unroll
          for (int tap = 0; tap < 9; tap++){
            u32 f = ctlw >> (3*tap);
            float s01 = (f & 1u) ? pc0[tap] : pc1[tap];
            s01 = __uint_as_float(__float_as_uint(s01) ^ ((f & 2u) << 30));
            float t2 = __uint_as_float(__float_as_uint(xv[2][tap]) ^ ((f & 4u) << 29));
            acc = __fadd_rn(acc, __fadd_rn(s01, t2));
          }
          float v = __fadd_rn(acc, c1b[co]);
          float t = bn_ts(v, __fmul_rn(g1[co], rs), bt1[co]);
          outw |= ((u32)(unsigned char)tsign(t)) << (8*j);
        }
        *reinterpret_cast<u32*>(&s1[pixbase + co4]) = outw;
      }
    } else {
      for (int co4 = 0; co4 < 32; co4 += 4){
        u32 outw = 0;
        #pragma unroll
        for (int j = 0; j < 4; j++){
          int co = coh*32 + co4 + j;
          u32 wA = wp1[co*2], wS = wp1[co*2+1];
          float acc = 0.f;
          #pragma unroll
          for (int tap = 0; tap < 9; tap++){
            float pt = 0.f;
            #pragma unroll
            for (int ci = 0; ci < 3; ci++){
              int bit = tap*3 + ci;
              float sg = ((wA >> bit) & 1u) ? (((wS >> bit) & 1u) ? 1.f : -1.f) : 0.f;
              pt = __fadd_rn(pt, __fmul_rn(sg, xv[ci][tap]));
            }
            acc = __fadd_rn(acc, pt);
          }
          float v = __fadd_rn(acc, c1b[co]);
          float t = bn_ts(v, __fmul_rn(g1[co], rs), bt1[co]);
          outw |= ((u32)(unsigned char)tsign(t)) << (8*j);
        }
        *reinterpret_cast<u32*>(&s1[pixbase + co4]) = outw;
      }
    }
  } else if (b < 3712){
    // -------- conv-weight MFMA fragment pack; float4 loads + uint4 stores --
    int bb = b - 2048;
    const float* w; s8* wf; int CIN, COUT, co;
    if      (bb < 128) { w=w2; wf=wf2; CIN=128; COUT=128; co=bb; }
    else if (bb < 384) { w=w3; wf=wf3; CIN=128; COUT=256; co=bb-128; }
    else if (bb < 640) { w=w4; wf=wf4; CIN=256; COUT=256; co=bb-384; }
    else if (bb < 1152){ w=w5; wf=wf5; CIN=256; COUT=512; co=bb-640; }
    else               { w=w6; wf=wf6; CIN=512; COUT=512; co=bb-1152; }
    s8* sb = (s8*)smraw;
    int nf = CIN*9;                           // divisible by 4
    const float4* wb4 = reinterpret_cast<const float4*>(w + (size_t)co*nf);
    for (int i = tid; i < nf/4; i += 256){
      float4 v4 = wb4[i];
      u32 pk = enc_sign(v4.x) | (enc_sign(v4.y) << 8)
             | (enc_sign(v4.z) << 16) | (enc_sign(v4.w) << 24);
      reinterpret_cast<u32*>(sb)[i] = pk;
    }
    __syncthreads();
    int KK = CIN >> 5, CG = COUT >> 5;
    int cg = co >> 5, llo = co & 31;
    int items = 9*KK*2;                       // (tap, kk, kh) triples
    for (int it = tid; it < items; it += 256){
      int tap = it % 9; int r = it / 9;
      int kh = r & 1; int kk = r >> 1;
      u32 wd[4];
      #pragma unroll
      for (int q = 0; q < 4; q++){
        u32 v = 0;
        #pragma unroll
        for (int e = 0; e < 4; e++){
          unsigned char bch = (unsigned char)sb[(kk*32 + kh*16 + q*4 + e)*9 + tap];
          v |= ((u32)bch) << (8*e);
        }
        wd[q] = v;
      }
      size_t dstb = ((((size_t)tap*KK + kk)*CG + cg)*64 + (llo + kh*32))*16;
      uint4 st = { wd[0], wd[1], wd[2], wd[3] };
      *reinterpret_cast<uint4*>(wf + dstb) = st;
    }
  } else if (b < 4736){
    // -------- fc1 pack (float4 loads): k = c*16 + px, kw = px*16 + cw ------
    int co = b - 3712;
    unsigned char* sb = (unsigned char*)smraw;
    const float4* wb4 = reinterpret_cast<const float4*>(fw1 + (size_t)co*8192);
    for (int i = tid; i < 2048; i += 256){
      float4 v4 = wb4[i];
      u32 pk = enc_bch(v4.x) | (enc_bch(v4.y) << 8)
             | (enc_bch(v4.z) << 16) | (enc_bch(v4.w) << 24);
      reinterpret_cast<u32*>(sb)[i] = pk;
    }
    __syncthreads();
    int kw = tid;
    int px = kw >> 4, cw = kw & 15;
    u32 a = 0, s = 0;
    for (int j = 0; j < 32; j++){
      unsigned char bch = sb[(cw*32 + j)*16 + px];
      a |= (u32)(bch >> 1) << j;
      s |= (u32)(bch & 1u) << j;
    }
    size_t o = ((size_t)kw*1024 + co)*2;
    fw1p[o] = a; fw1p[o+1] = s;
  } else if (b < 5770){
    // -------- fw2 + fw3 bitplane pack (float4 loads) -----------------------
    int bb = b - 4736;
    const float* w; u32* wp; int COUT, co;
    if (bb < 1024){ w = fw2; wp = fw2p; COUT = 1024; co = bb; }
    else          { w = fw3; wp = fw3p; COUT = 10;   co = bb-1024; }
    unsigned char* sb = (unsigned char*)smraw;
    const float4* wb4 = reinterpret_cast<const float4*>(w + (size_t)co*1024);
    if (tid < 256){
      float4 v4 = wb4[tid];
      u32 pk = enc_bch(v4.x) | (enc_bch(v4.y) << 8)
             | (enc_bch(v4.z) << 16) | (enc_bch(v4.w) << 24);
      reinterpret_cast<u32*>(sb)[tid] = pk;
    }
    __syncthreads();
    for (int kw = tid; kw < 32; kw += 256){
      u32 a = 0, s = 0;
      for (int j = 0; j < 32; j++){
        unsigned char bch = sb[kw*32 + j];
        a |= (u32)(bch >> 1) << j;
        s |= (u32)(bch & 1u) << j;
      }
      size_t o = ((size_t)kw*COUT + co)*2;
      wp[o] = a; wp[o+1] = s;
    }
  } else {
    // ---------------- per-channel scales ------------------------------------
    int i = (b - 5770)*256 + tid;
    const float rs = __fdiv_rn(1.0f, __fsqrt_rn((float)(1.0 + 1e-5)));
    float v;
    if      (i < 128)  v = g1[i];
    else if (i < 256)  v = g2[i-128];
    else if (i < 512)  v = g3[i-256];
    else if (i < 768)  v = g4[i-512];
    else if (i < 1280) v = g5[i-768];
    else if (i < 1792) v = g6[i-1280];
    else if (i < 2816) v = gf1[i-1792];
    else if (i < 3840) v = gf2[i-2816];
    else if (i < 3850) v = gf3[i-3840];
    else return;
    scb[i] = __fmul_rn(v, rs);
  }
}

// ---------------------------------------------------------------------------
// MFMA ternary bconv: CGB=2, block-shared cout-group, per-tap B-slice staged
// global->LDS double-buffered. PT pixel tiles per wave (r19 config).
// ---------------------------------------------------------------------------
template<int CIN, int COUT, int H, int W, int POOL, int BITOUT, int WPB, int PT>
__global__ __launch_bounds__(WPB*64) void bconv_l(
    const s8* __restrict__ A, const s8* __restrict__ WF,
    const float* __restrict__ sc, const float* __restrict__ bt,
    s8* __restrict__ O, u32* __restrict__ OB){
  constexpr int KK = CIN/32, CG = COUT/32, CGB = 2;
  constexpr int XT = (W >= 16) ? 16 : 8;
  constexpr int YT = 32 / XT;
  constexpr int TPR = W / XT;
  constexpr int TROWS = H / YT;
  constexpr int NMT = 128*TROWS*TPR;
  constexpr int NTG = NMT / PT;              // tile-groups (1 group / wave)
  constexpr int HO = POOL ? H/2 : H, WO = POOL ? W/2 : W;
  constexpr int RY = (XT == 16) ? 8 : 4;
  constexpr int TAPB = KK*CGB*1024;          // bytes per tap B-slice
  constexpr int NT = WPB*64;
  __shared__ s8 Bsh[2][TAPB];

  int tid = threadIdx.x, lane = tid & 63, wv = tid >> 6;
  int wid = blockIdx.x*WPB + wv;
  int mtg = wid % NTG; int cb = wid / NTG;   // NTG%WPB==0 -> cb uniform/block
  int p = lane & 31;
  int py = p / XT, px = p % XT;
  int kh = lane >> 5;

  // per-tile coordinates
  int y0t[PT], x0t[PT], nt[PT];
  #pragma unroll
  for (int t = 0; t < PT; t++){
    int mt = mtg*PT + t;
    int tx = mt % TPR; int r0 = mt / TPR;
    int ty = r0 % TROWS; nt[t] = r0 / TROWS;
    y0t[t] = ty*YT; x0t[t] = tx*XT;
  }

  auto stage = [&](int buf, int tap){
    const s8* src0 = WF + (((size_t)tap*KK)*CG + (size_t)cb*CGB)*1024;
    #pragma unroll
    for (int j = 0; j < TAPB/(NT*16); j++){
      int byte = (tid + j*NT)*16;
      int kk = byte / (CGB*1024);
      int rem = byte - kk*(CGB*1024);
      *reinterpret_cast<uint4*>(&Bsh[buf][byte]) =
        *reinterpret_cast<const uint4*>(src0 + (size_t)kk*CG*1024 + rem);
    }
  };

  i32x16 accA0 = {0,0,0,0,0,0,0,0,0,0,0,0,0,0,0,0};
  i32x16 accA1 = accA0, accB0 = accA0, accB1 = accA0;

  stage(0, 0);
  __syncthreads();
  int buf = 0;
  #pragma unroll
  for (int tap = 0; tap < 9; tap++){
    if (tap < 8) stage(buf^1, tap+1);        // overlap next-tap staging
    int dy = tap/3 - 1, dx = tap%3 - 1;
    int syA = y0t[0] + py + dy, sxA = x0t[0] + px + dx;
    bool okA = ((unsigned)syA < (unsigned)H) && ((unsigned)sxA < (unsigned)W);
    const s8* apA = A + (((size_t)nt[0]*H + syA)*W + sxA)*CIN + kh*16;
    const s8* apB = nullptr; bool okB = false;
    if (PT == 2){
      int syB = y0t[1] + py + dy, sxB = x0t[1] + px + dx;
      okB = ((unsigned)syB < (unsigned)H) && ((unsigned)sxB < (unsigned)W);
      apB = A + (((size_t)nt[1]*H + syB)*W + sxB)*CIN + kh*16;
    }
    #pragma unroll
    for (int kk = 0; kk < KK; kk++){
      i32x4 avA = {0,0,0,0};
      if (okA) avA = *reinterpret_cast<const i32x4*>(apA + kk*32);
      i32x4 b0 = *reinterpret_cast<const i32x4*>(&Bsh[buf][(kk*CGB+0)*1024 + lane*16]);
      i32x4 b1 = *reinterpret_cast<const i32x4*>(&Bsh[buf][(kk*CGB+1)*1024 + lane*16]);
      accA0 = __builtin_amdgcn_mfma_i32_32x32x32_i8(avA, b0, accA0, 0, 0, 0);
      accA1 = __builtin_amdgcn_mfma_i32_32x32x32_i8(avA, b1, accA1, 0, 0, 0);
      if (PT == 2){
        i32x4 avB = {0,0,0,0};
        if (okB) avB = *reinterpret_cast<const i32x4*>(apB + kk*32);
        accB0 = __builtin_amdgcn_mfma_i32_32x32x32_i8(avB, b0, accB0, 0, 0, 0);
        accB1 = __builtin_amdgcn_mfma_i32_32x32x32_i8(avB, b1, accB1, 0, 0, 0);
      }
    }
    __syncthreads();                          // staged writes visible
    buf ^= 1;
  }

  auto epi = [&](const i32x16& acc, int cgb, int y0, int x0, int n){
    int co = (cb*CGB + cgb)*32 + (lane & 31);
    float ss = sc[co], bb = bt[co];
    if (POOL){
      #pragma unroll
      for (int q = 0; q < 4; q++){
        int rr = (q&1)*2 + (q>>1)*((XT == 16) ? 4 : 8);
        int z = max(max(acc[rr], acc[rr+1]), max(acc[rr+RY], acc[rr+RY+1]));
        float t = bn_ts((float)z, ss, bb);
        if (!BITOUT){
          int pb = (rr&3) + 8*(rr>>2) + 4*kh;
          int yy = y0 + pb/XT, xx2 = x0 + pb%XT;
          int oy = yy >> 1, ox = xx2 >> 1;
          O[(((size_t)n*HO + oy)*WO + ox)*COUT + co] = tsign(t);
        } else {
          u64 mP = __ballot(t > 0.f);
          u64 mN = __ballot(t < 0.f);
          if (lane == 0){
            u64 mA = mP | mN;
            int cw = cb*CGB + cgb;
            int pb0 = (rr&3) + 8*(rr>>2);
            int yy0 = y0 + pb0/XT, xx0 = x0 + pb0%XT;
            int p0 = (yy0>>1)*4 + (xx0>>1);
            int pb1 = pb0 + 4;
            int yy1 = y0 + pb1/XT, xx1 = x0 + pb1%XT;
            int p1 = (yy1>>1)*4 + (xx1>>1);
            size_t o0 = ((size_t)n*256 + p0*16 + cw)*2;
            size_t o1 = ((size_t)n*256 + p1*16 + cw)*2;
            OB[o0]   = (u32)mA;       OB[o0+1] = (u32)mP;
            OB[o1]   = (u32)(mA>>32); OB[o1+1] = (u32)(mP>>32);
          }
        }
      }
    } else {
      #pragma unroll
      for (int rr = 0; rr < 16; rr++){
        int pb = (rr&3) + 8*(rr>>2) + 4*kh;
        int yy = y0 + pb/XT, xx2 = x0 + pb%XT;
        float t = bn_ts((float)acc[rr], ss, bb);
        O[(((size_t)n*H + yy)*W + xx2)*COUT + co] = tsign(t);
      }
    }
  };
  epi(accA0, 0, y0t[0], x0t[0], nt[0]);
  epi(accA1, 1, y0t[0], x0t[0], nt[0]);
  if (PT == 2){
    epi(accB0, 0, y0t[1], x0t[1], nt[1]);
    epi(accB1, 1, y0t[1], x0t[1], nt[1]);
  }
}

// ---------------------------------------------------------------------------
// Ternary FC + threshold + ternary ballot (bitplanes).
// ---------------------------------------------------------------------------
template<int KW>
__global__ __launch_bounds__(256) void fcb_k(
    const u32* __restrict__ A, const u32* __restrict__ Wp,
    const float* __restrict__ fb,
    const float* __restrict__ sc, const float* __restrict__ bt,
    u32* __restrict__ Op){
  int tid = threadIdx.x; int lane = tid & 63; int wv = tid >> 6;
  int wid = blockIdx.x*4 + wv;          // 128*16 waves
  int og = wid & 15; int n = wid >> 4;
  int o = og*64 + lane;
  const uint2* a = reinterpret_cast<const uint2*>(&A[(size_t)n*KW*2]);
  int z = 0;
  #pragma unroll 8
  for (int kw = 0; kw < KW; kw++){
    uint2 av = a[kw];
    uint2 wv_ = reinterpret_cast<const uint2*>(Wp)[kw*1024 + o];
    u32 v = av.x & wv_.x;
    u32 d = v & (av.y ^ wv_.y);
    z += __popc(v) - 2*__popc(d);
  }
  float vv = __fadd_rn((float)z, fb[o]);
  float t = bn_ts(vv, sc[o], bt[o]);
  u64 mP = __ballot(t > 0.f);
  u64 mN = __ballot(t < 0.f);
  if (lane == 0){
    int ob = (n*32 + og*2)*2;
    Op[ob]   = (u32)(mP | mN);
    Op[ob+1] = (u32)mP;
    Op[ob+2] = (u32)((mP | mN) >> 32);
    Op[ob+3] = (u32)(mP >> 32);
  }
}

// fc3 (10 outputs) + bn + log_softmax -> f32 out [128][10]
__global__ void fc3_k(const u32* __restrict__ A, const u32* __restrict__ Wp,
                      const float* __restrict__ fb,
                      const float* __restrict__ sc,
                      const float* __restrict__ bt,
                      float* __restrict__ out){
  int n = blockIdx.x; int lane = threadIdx.x;   // blockDim = 64
  __shared__ double ls[10];
  double t = 0.0;
  if (lane < 10){
    const uint2* a = reinterpret_cast<const uint2*>(&A[(size_t)n*32*2]);
    int z = 0;
    for (int kw = 0; kw < 32; kw++){
      uint2 av = a[kw];
      uint2 wv_ = reinterpret_cast<const uint2*>(Wp)[kw*10 + lane];
      u32 v = av.x & wv_.x;
      u32 d = v & (av.y ^ wv_.y);
      z += __popc(v) - 2*__popc(d);
    }
    float vv = __fadd_rn((float)z, fb[lane]);
    float tf = bn_ts(vv, sc[lane], bt[lane]);
    t = (double)tf;
    ls[lane] = t;
  }
  __syncthreads();
  if (lane < 10){
    double m = -1e300;
    for (int j = 0; j < 10; j++) m = fmax(m, ls[j]);
    double sum = 0.0;
    for (int j = 0; j < 10; j++) sum += exp(ls[j] - m);
    double r = t - m - log(sum);
    out[n*10 + lane] = (float)r;
  }
}

extern "C" void kernel_launch(void* const* d_in, const int* in_sizes, int n_in,
                              void* d_out, int out_size, void* d_ws, size_t ws_size,
                              hipStream_t stream){
  auto f = [&](int i){ return (const float*)d_in[i]; };
  const float *x  = f(0),  *w1 = f(1),  *c1b = f(2),
    *w2 = f(3),  *w3 = f(4),  *w4 = f(5),  *w5 = f(6),  *w6 = f(7),
    *fw1 = f(8), *fb1 = f(9), *fw2 = f(10), *fb2 = f(11),
    *fw3 = f(12), *fb3 = f(13),
    *g1 = f(14), *bt1 = f(15), *g2 = f(16), *bt2 = f(17),
    *g3 = f(18), *bt3 = f(19), *g4 = f(20), *bt4 = f(21),
    *g5 = f(22), *bt5 = f(23), *g6 = f(24), *bt6 = f(25),
    *gf1 = f(26), *btf1 = f(27), *gf2 = f(28), *btf2 = f(29),
    *gf3 = f(30), *btf3 = f(31);

  char* base = (char*)d_ws;
  size_t off = 0;
  auto alloc = [&](size_t bytes){ char* p = base + off; off += (bytes + 255) & ~(size_t)255; return p; };
  s8* poolA = (s8*)alloc(128ull*32*32*128);       // s1 / s3 / s5
  s8* poolB = (s8*)alloc(128ull*16*16*128);       // s2 / s4
  s8 *s1 = poolA, *s3 = poolA, *s5 = poolA;
  s8 *s2 = poolB, *s4 = poolB;
  s8 *wf2 = (s8*)alloc(9ull*128*128), *wf3 = (s8*)alloc(9ull*128*256),
     *wf4 = (s8*)alloc(9ull*256*256), *wf5 = (s8*)alloc(9ull*256*512),
     *wf6 = (s8*)alloc(9ull*512*512);
  u32 *wp1  = (u32*)alloc(385*4);                 // bitplanes + ctl + flag
  float* scb = (float*)alloc(3850*4);             // per-channel scales
  u32 *fw1p = (u32*)alloc(2ull*256*1024*4), *fw2p = (u32*)alloc(2ull*32*1024*4),
      *fw3p = (u32*)alloc(2ull*32*10*4);
  u32 *s6p  = (u32*)alloc(2ull*128*256*4);
  u32 *sf1  = (u32*)alloc(2ull*128*32*4), *sf2 = (u32*)alloc(2ull*128*32*4);

  float *sc2 = scb+128, *sc3 = scb+256, *sc4 = scb+512,
        *sc5 = scb+768, *sc6 = scb+1280, *scf1 = scb+1792, *scf2 = scb+2816,
        *scf3 = scb+3840;

  // dispatch 1: tiny w1 pack (conv1 in mega depends on it)
  pack_w1_k<<<1, 64, 0, stream>>>(w1, wp1);
  // dispatch 2: conv1 || all weight packing || scales
  mega_k<<<5786, 256, 0, stream>>>(
      x, wp1, c1b, g1, bt1, s1,
      w2, w3, w4, w5, w6, wf2, wf3, wf4, wf5, wf6,
      fw1, fw1p, fw2, fw3, fw2p, fw3p,
      g2, g3, g4, g5, g6, gf1, gf2, gf3, scb);

  // network — blocks = NTG*(CG/2)/WPB
  bconv_l<128,128,32,32,1,0,4,2><<<1024, 256, 0, stream>>>(s1, wf2, sc2, bt2, s2, nullptr);
  bconv_l<128,256,16,16,0,0,4,2><<< 512, 256, 0, stream>>>(s2, wf3, sc3, bt3, s3, nullptr);
  bconv_l<256,256,16,16,1,0,4,2><<< 512, 256, 0, stream>>>(s3, wf4, sc4, bt4, s4, nullptr);
  bconv_l<256,512, 8, 8,0,0,4,1><<< 512, 256, 0, stream>>>(s4, wf5, sc5, bt5, s5, nullptr);
  bconv_l<512,512, 8, 8,1,1,4,1><<< 512, 256, 0, stream>>>(s5, wf6, sc6, bt6, nullptr, s6p);
  fcb_k<256><<<(128*16)/4, 256, 0, stream>>>(s6p, fw1p, fb1, scf1, btf1, sf1);
  fcb_k<32><<<(128*16)/4,  256, 0, stream>>>(sf1, fw2p, fb2, scf2, btf2, sf2);
  fc3_k<<<128, 64, 0, stream>>>(sf2, fw3p, fb3, scf3, btf3, (float*)d_out);
}